// Round 8
// baseline (598.420 us; speedup 1.0000x reference)
//
#include <hip/hip_runtime.h>
#include <hip/hip_bf16.h>

typedef __bf16 bf16;
typedef __bf16 bf16x8 __attribute__((ext_vector_type(8)));
typedef float f32x4 __attribute__((ext_vector_type(4)));

// ---------------- weight fp32 -> bf16 convert ----------------
__global__ void cvt_weights(const float* __restrict__ wq, const float* __restrict__ wkv,
                            const float* __restrict__ wp, const float* __restrict__ w1,
                            const float* __restrict__ w2,
                            bf16* __restrict__ wqkv, bf16* __restrict__ wpb,
                            bf16* __restrict__ w1b, bf16* __restrict__ w2b) {
  int i = blockIdx.x * 256 + threadIdx.x;
  if (i < 65536) wqkv[i] = (bf16)wq[i];
  else if (i < 131072) wqkv[i] = (bf16)wkv[i - 65536];
  else if (i < 196608) wpb[i - 131072] = (bf16)wp[i - 131072];
  else if (i < 458752) w1b[i - 196608] = (bf16)w1[i - 196608];
  else if (i < 720896) w2b[i - 458752] = (bf16)w2[i - 458752];
}

// ---------------- LayerNorm (wave per row, rows of 256) ----------------
__launch_bounds__(256)
__global__ void ln_kernel(const float* __restrict__ x, const float* __restrict__ g,
                          const float* __restrict__ b, bf16* __restrict__ out) {
  const int row = blockIdx.x * 4 + (threadIdx.x >> 6);
  const int lane = threadIdx.x & 63;
  const float4 v = ((const float4*)(x + (long)row * 256))[lane];
  float s = v.x + v.y + v.z + v.w;
#pragma unroll
  for (int o = 1; o < 64; o <<= 1) s += __shfl_xor(s, o);
  const float mu = s * (1.f / 256.f);
  const float dx = v.x - mu, dy = v.y - mu, dz = v.z - mu, dw = v.w - mu;
  float q = dx * dx + dy * dy + dz * dz + dw * dw;
#pragma unroll
  for (int o = 1; o < 64; o <<= 1) q += __shfl_xor(q, o);
  const float rstd = rsqrtf(q * (1.f / 256.f) + 1e-5f);
  const float4 gg = ((const float4*)g)[lane];
  const float4 bb = ((const float4*)b)[lane];
  union { bf16 h[4]; uint2 u; } pk;
  pk.h[0] = (bf16)(dx * rstd * gg.x + bb.x);
  pk.h[1] = (bf16)(dy * rstd * gg.y + bb.y);
  pk.h[2] = (bf16)(dz * rstd * gg.z + bb.z);
  pk.h[3] = (bf16)(dw * rstd * gg.w + bb.w);
  *(uint2*)(out + (long)row * 256 + lane * 4) = pk.u;
}

// ---------------- register-direct GEMM, K=256 ----------------
// No LDS, no barriers. Each wave owns a 32x64 output tile per m-iter (FM=2, FN=4, MIT=2).
// B slice (64 cols x 256 K) persistent in 128 VGPRs; A fragments loaded global->VGPR
// (16 rows x 64B sectors per instr — same sector count as coalesced).
// Slot order: cg-siblings of one 64-row A strip adjacent on one XCD -> A from HBM once.
// EPI 0: bf16 store. 1: f32 acc+bias+res. 2: bf16 gelu(acc+bias).
template <int EPI, int NCG, int NBLK>
__launch_bounds__(256, 2)
__global__ void gemm_reg(const bf16* __restrict__ A, const bf16* __restrict__ Bw,
                         void* C, const float* __restrict__ bias,
                         const float* __restrict__ res, int ldC) {
  const int tid = threadIdx.x, w = tid >> 6, lane = tid & 63;
  const int l15 = lane & 15, l4 = lane >> 4;
  const int bid = blockIdx.x;
  const int slot4 = ((bid & 7) * (NBLK / 8) + (bid >> 3)) * 4 + w;
  const int cg = slot4 % NCG;
  const long row0 = (long)(slot4 / NCG) * 64;
  const int c0 = cg * 64;

  bf16x8 Breg[8][4];
  {
    const bf16* Bp = Bw + ((long)c0 + l15) * 256 + l4 * 8;
#pragma unroll
    for (int kl = 0; kl < 8; ++kl)
#pragma unroll
      for (int fn = 0; fn < 4; ++fn)
        Breg[kl][fn] = *(const bf16x8*)(Bp + fn * (16 * 256) + kl * 32);
  }
  float biasr[4];
  if constexpr (EPI != 0) {
#pragma unroll
    for (int fn = 0; fn < 4; ++fn) biasr[fn] = bias[c0 + fn * 16 + l15];
  }

#pragma unroll
  for (int mi = 0; mi < 2; ++mi) {
    const long r0 = row0 + mi * 32;
    bf16x8 Areg[2][8];
    const bf16* Ap = A + (r0 + l15) * 256 + l4 * 8;
#pragma unroll
    for (int fm = 0; fm < 2; ++fm)
#pragma unroll
      for (int kl = 0; kl < 8; ++kl)
        Areg[fm][kl] = *(const bf16x8*)(Ap + fm * (16 * 256) + kl * 32);
    f32x4 acc[2][4] = {};
#pragma unroll
    for (int kl = 0; kl < 8; ++kl)
#pragma unroll
      for (int fm = 0; fm < 2; ++fm)
#pragma unroll
        for (int fn = 0; fn < 4; ++fn)
          acc[fm][fn] = __builtin_amdgcn_mfma_f32_16x16x32_bf16(Areg[fm][kl], Breg[kl][fn],
                                                                acc[fm][fn], 0, 0, 0);
#pragma unroll
    for (int fm = 0; fm < 2; ++fm)
#pragma unroll
      for (int fn = 0; fn < 4; ++fn)
#pragma unroll
        for (int r = 0; r < 4; ++r) {
          const long row = r0 + fm * 16 + l4 * 4 + r;
          const long col = c0 + fn * 16 + l15;
          const long idx = row * ldC + col;
          const float v = acc[fm][fn][r];
          if constexpr (EPI == 0) {
            ((bf16*)C)[idx] = (bf16)v;
          } else if constexpr (EPI == 1) {
            ((float*)C)[idx] = v + biasr[fn] + res[idx];
          } else {
            const float t = v + biasr[fn];
            ((bf16*)C)[idx] = (bf16)(0.5f * t * (1.f + erff(t * 0.70710678118654752f)));
          }
        }
  }
}

// ---------------- register-direct mlp2 GEMM, K=1024, in-place RMW epilogue ----------------
// out[65536x256] = out + hidden @ W2^T + b2 (out holds x2). B streamed per K-chunk of 256.
__launch_bounds__(256, 2)
__global__ void gemm_mlp2(const bf16* __restrict__ A, const bf16* __restrict__ Bw,
                          float* __restrict__ C, const float* __restrict__ bias) {
  constexpr int NBLK = 1024, NCG = 4;
  const int tid = threadIdx.x, w = tid >> 6, lane = tid & 63;
  const int l15 = lane & 15, l4 = lane >> 4;
  const int bid = blockIdx.x;
  const int slot4 = ((bid & 7) * (NBLK / 8) + (bid >> 3)) * 4 + w;
  const int cg = slot4 % NCG;
  const long row0 = (long)(slot4 / NCG) * 64;
  const int c0 = cg * 64;
  float biasr[4];
#pragma unroll
  for (int fn = 0; fn < 4; ++fn) biasr[fn] = bias[c0 + fn * 16 + l15];

#pragma unroll
  for (int mi = 0; mi < 2; ++mi) {
    const long r0 = row0 + mi * 32;
    f32x4 acc[2][4] = {};
    for (int kc = 0; kc < 4; ++kc) {
      bf16x8 Breg[8][4];
      const bf16* Bp = Bw + ((long)c0 + l15) * 1024 + kc * 256 + l4 * 8;
#pragma unroll
      for (int kl = 0; kl < 8; ++kl)
#pragma unroll
        for (int fn = 0; fn < 4; ++fn)
          Breg[kl][fn] = *(const bf16x8*)(Bp + fn * (16 * 1024) + kl * 32);
      bf16x8 Areg[2][8];
      const bf16* Ap = A + (r0 + l15) * 1024 + kc * 256 + l4 * 8;
#pragma unroll
      for (int fm = 0; fm < 2; ++fm)
#pragma unroll
        for (int kl = 0; kl < 8; ++kl)
          Areg[fm][kl] = *(const bf16x8*)(Ap + fm * (16 * 1024) + kl * 32);
#pragma unroll
      for (int kl = 0; kl < 8; ++kl)
#pragma unroll
        for (int fm = 0; fm < 2; ++fm)
#pragma unroll
          for (int fn = 0; fn < 4; ++fn)
            acc[fm][fn] = __builtin_amdgcn_mfma_f32_16x16x32_bf16(Areg[fm][kl], Breg[kl][fn],
                                                                  acc[fm][fn], 0, 0, 0);
    }
#pragma unroll
    for (int fm = 0; fm < 2; ++fm)
#pragma unroll
      for (int fn = 0; fn < 4; ++fn)
#pragma unroll
        for (int r = 0; r < 4; ++r) {
          const long row = r0 + fm * 16 + l4 * 4 + r;
          const long idx = row * 256 + c0 + fn * 16 + l15;
          C[idx] = C[idx] + acc[fm][fn][r] + biasr[fn];
        }
  }
}

// ---------------- local window attention (head 0), one block per (window, batch) ----------------
__launch_bounds__(256)
__global__ void lattn_kernel(const bf16* __restrict__ qkv, bf16* __restrict__ attn) {
  const int j = blockIdx.x, b = blockIdx.y;
  const int tid = threadIdx.x, w = tid >> 6, lane = tid & 63;
  __shared__ bf16 Qs[64 * 40];
  __shared__ bf16 Ks[192 * 40];
  __shared__ bf16 Kt[32 * 200];
  __shared__ bf16 Ps[4][16 * 200];
  const float scale = 0.17677669529663687f;
  const long base = (long)b * 8192 + (long)j * 64;
  for (int i = tid; i < 64 * 32; i += 256) {
    const int r = i >> 5, d = i & 31;
    Qs[r * 40 + d] = (bf16)((float)qkv[(base + r) * 512 + d] * scale);
  }
  for (int i = tid; i < 192 * 32; i += 256) {
    const int c = i >> 5, d = i & 31;
    const long tc = (long)j * 64 - 64 + c;
    float kv = 0.f;
    if (tc >= 0 && tc < 8192) kv = (float)qkv[((long)b * 8192 + tc) * 512 + 256 + d];
    const bf16 kb = (bf16)kv;
    Ks[c * 40 + d] = kb;
    Kt[d * 200 + c] = kb;
  }
  __syncthreads();
  const int l15 = lane & 15, l4 = lane >> 4;
  const bf16x8 aq = *(const bf16x8*)(Qs + (w * 16 + l15) * 40 + l4 * 8);
  const f32x4 zz = {0.f, 0.f, 0.f, 0.f};
  f32x4 S[12];
#pragma unroll
  for (int fn = 0; fn < 12; ++fn) {
    const bf16x8 bk = *(const bf16x8*)(Ks + (fn * 16 + l15) * 40 + l4 * 8);
    S[fn] = __builtin_amdgcn_mfma_f32_16x16x32_bf16(aq, bk, zz, 0, 0, 0);
  }
#pragma unroll
  for (int fn = 0; fn < 12; ++fn) {
    const long tc = (long)j * 64 - 64 + fn * 16 + l15;
    if (tc < 0 || tc >= 8192) { S[fn][0] = -1e9f; S[fn][1] = -1e9f; S[fn][2] = -1e9f; S[fn][3] = -1e9f; }
  }
  float sinv[4];
#pragma unroll
  for (int r = 0; r < 4; ++r) {
    float m = -1e30f;
#pragma unroll
    for (int fn = 0; fn < 12; ++fn) m = fmaxf(m, S[fn][r]);
#pragma unroll
    for (int o = 1; o < 16; o <<= 1) m = fmaxf(m, __shfl_xor(m, o));
    float s = 0.f;
#pragma unroll
    for (int fn = 0; fn < 12; ++fn) { const float e = __expf(S[fn][r] - m); S[fn][r] = e; s += e; }
#pragma unroll
    for (int o = 1; o < 16; o <<= 1) s += __shfl_xor(s, o);
    sinv[r] = 1.f / s;
  }
#pragma unroll
  for (int fn = 0; fn < 12; ++fn)
#pragma unroll
    for (int r = 0; r < 4; ++r)
      Ps[w][(l4 * 4 + r) * 200 + fn * 16 + l15] = (bf16)(S[fn][r] * sinv[r]);
  __syncthreads();
  f32x4 O[2] = {};
#pragma unroll
  for (int ks = 0; ks < 6; ++ks) {
    const bf16x8 ap = *(const bf16x8*)(Ps[w] + l15 * 200 + ks * 32 + l4 * 8);
#pragma unroll
    for (int fe = 0; fe < 2; ++fe) {
      const bf16x8 bv = *(const bf16x8*)(Kt + (fe * 16 + l15) * 200 + ks * 32 + l4 * 8);
      O[fe] = __builtin_amdgcn_mfma_f32_16x16x32_bf16(ap, bv, O[fe], 0, 0, 0);
    }
  }
#pragma unroll
  for (int fe = 0; fe < 2; ++fe)
#pragma unroll
    for (int r = 0; r < 4; ++r)
      attn[(base + w * 16 + l4 * 4 + r) * 256 + fe * 16 + l15] = (bf16)O[fe][r];
}

// ---------------- linear attn ctx via MFMA (S via ones-row) ----------------
__launch_bounds__(256)
__global__ void ctx_kernel(const bf16* __restrict__ qkv, float* __restrict__ ctx,
                           float* __restrict__ S) {
  const int bh = blockIdx.x;
  const int b = bh / 7, h = bh % 7 + 1;
  const int tid = threadIdx.x;
  const int w = tid >> 6, lane = tid & 63;
  const int l15 = lane & 15, l4 = lane >> 4;
  __shared__ bf16 evT[32 * 264];
  __shared__ bf16 kT[48 * 264];
  __shared__ float red[4][32 * 48];
  const long n0 = (long)blockIdx.y * 256;
  const bf16* kp = qkv + ((long)b * 8192 + n0 + tid) * 512 + 256 + h * 32;
  bf16x8 kv[4];
#pragma unroll
  for (int c = 0; c < 4; ++c) kv[c] = *(const bf16x8*)(kp + c * 8);
#pragma unroll
  for (int i = 0; i < 16; ++i)
    kT[(32 + i) * 264 + tid] = (i == 0) ? (bf16)1.0f : (bf16)0.0f;
#pragma unroll
  for (int c = 0; c < 4; ++c)
#pragma unroll
    for (int j = 0; j < 8; ++j) {
      const int d = c * 8 + j;
      evT[d * 264 + tid] = (bf16)__expf((float)kv[c][j]);
      kT[d * 264 + tid] = kv[c][j];
    }
  __syncthreads();
  f32x4 acc[2][3] = {};
#pragma unroll
  for (int ks = 0; ks < 2; ++ks) {
    const int ncol = w * 64 + ks * 32 + l4 * 8;
    bf16x8 af[2], bb[3];
#pragma unroll
    for (int fm = 0; fm < 2; ++fm) af[fm] = *(const bf16x8*)(evT + (fm * 16 + l15) * 264 + ncol);
#pragma unroll
    for (int fe = 0; fe < 3; ++fe) bb[fe] = *(const bf16x8*)(kT + (fe * 16 + l15) * 264 + ncol);
#pragma unroll
    for (int fm = 0; fm < 2; ++fm)
#pragma unroll
      for (int fe = 0; fe < 3; ++fe)
        acc[fm][fe] = __builtin_amdgcn_mfma_f32_16x16x32_bf16(af[fm], bb[fe], acc[fm][fe], 0, 0, 0);
  }
#pragma unroll
  for (int fm = 0; fm < 2; ++fm)
#pragma unroll
    for (int fe = 0; fe < 3; ++fe)
#pragma unroll
      for (int r = 0; r < 4; ++r)
        red[w][(fm * 16 + l4 * 4 + r) * 48 + fe * 16 + l15] = acc[fm][fe][r];
  __syncthreads();
  for (int i = tid; i < 32 * 48; i += 256) {
    const float v = red[0][i] + red[1][i] + red[2][i] + red[3][i];
    const int d = i / 48, e = i - d * 48;
    if (e < 32) atomicAdd(ctx + (long)bh * 1024 + d * 32 + e, v);
    else if (e == 32) atomicAdd(S + bh * 32 + d, v);
  }
}

// ---------------- linear attn out via register softmax + MFMA ----------------
__launch_bounds__(256)
__global__ void lout_kernel(const bf16* __restrict__ qkv, const float* __restrict__ S,
                            const float* __restrict__ ctx, bf16* __restrict__ attn) {
  const int bh = blockIdx.x;
  const int b = bh / 7, h = bh % 7 + 1;
  const int tid = threadIdx.x;
  const int w = tid >> 6, lane = tid & 63;
  const int l15 = lane & 15, l4 = lane >> 4;
  __shared__ bf16 qs[256 * 40];
  __shared__ bf16 C2t[32 * 40];
  const long n0 = (long)blockIdx.y * 256;
  for (int i = tid; i < 1024; i += 256) {
    const int e = i >> 5, d = i & 31;
    C2t[e * 40 + d] = (bf16)(ctx[(long)bh * 1024 + d * 32 + e] / S[bh * 32 + d]);
  }
  const bf16* qp = qkv + ((long)b * 8192 + n0 + tid) * 512 + h * 32;
  bf16x8 qv[4];
#pragma unroll
  for (int c = 0; c < 4; ++c) qv[c] = *(const bf16x8*)(qp + c * 8);
  float qf[32];
#pragma unroll
  for (int c = 0; c < 4; ++c)
#pragma unroll
    for (int j = 0; j < 8; ++j) qf[c * 8 + j] = (float)qv[c][j];
  float m = qf[0];
#pragma unroll
  for (int d = 1; d < 32; ++d) m = fmaxf(m, qf[d]);
  float s = 0.f;
#pragma unroll
  for (int d = 0; d < 32; ++d) { qf[d] = __expf(qf[d] - m); s += qf[d]; }
  const float f = 0.17677669529663687f / s;
#pragma unroll
  for (int c = 0; c < 4; ++c) {
    bf16x8 o;
#pragma unroll
    for (int j = 0; j < 8; ++j) o[j] = (bf16)(qf[c * 8 + j] * f);
    *(bf16x8*)(qs + tid * 40 + c * 8) = o;
  }
  __syncthreads();
  f32x4 acc[4][2] = {};
  bf16x8 bfr[2];
#pragma unroll
  for (int fe = 0; fe < 2; ++fe) bfr[fe] = *(const bf16x8*)(C2t + (fe * 16 + l15) * 40 + l4 * 8);
#pragma unroll
  for (int fm = 0; fm < 4; ++fm) {
    const bf16x8 af = *(const bf16x8*)(qs + (w * 64 + fm * 16 + l15) * 40 + l4 * 8);
#pragma unroll
    for (int fe = 0; fe < 2; ++fe)
      acc[fm][fe] = __builtin_amdgcn_mfma_f32_16x16x32_bf16(af, bfr[fe], acc[fm][fe], 0, 0, 0);
  }
#pragma unroll
  for (int fm = 0; fm < 4; ++fm)
#pragma unroll
    for (int fe = 0; fe < 2; ++fe)
#pragma unroll
      for (int r = 0; r < 4; ++r)
        attn[((long)b * 8192 + n0 + w * 64 + fm * 16 + l4 * 4 + r) * 256 + h * 32 + fe * 16 + l15]
            = (bf16)acc[fm][fe][r];
}

extern "C" void kernel_launch(void* const* d_in, const int* in_sizes, int n_in,
                              void* d_out, int out_size, void* d_ws, size_t ws_size,
                              hipStream_t stream) {
  const float* x     = (const float*)d_in[0];
  const float* n1g   = (const float*)d_in[1];
  const float* n1b   = (const float*)d_in[2];
  const float* Wq    = (const float*)d_in[3];
  const float* Wkv   = (const float*)d_in[4];
  const float* Wproj = (const float*)d_in[5];
  const float* bproj = (const float*)d_in[6];
  const float* n2g   = (const float*)d_in[7];
  const float* n2b   = (const float*)d_in[8];
  const float* W1    = (const float*)d_in[9];
  const float* b1    = (const float*)d_in[10];
  const float* W2    = (const float*)d_in[11];
  const float* b2    = (const float*)d_in[12];
  float* out = (float*)d_out;
  char* ws = (char*)d_ws;

  bf16* wqkv   = (bf16*)(ws + 0);
  bf16* wprojb = (bf16*)(ws + 262144);
  bf16* w1b    = (bf16*)(ws + 393216);
  bf16* w2b    = (bf16*)(ws + 917504);
  float* Sbuf  = (float*)(ws + 1441792);   // 56*32 f32, contiguous with ctx for one memset
  float* ctx   = (float*)(ws + 1448960);   // 56*1024 f32
  bf16* hbuf   = (bf16*)(ws + 1685504);    // 65536x256 bf16 (h1 -> attn -> h2)
  bf16* qkv    = (bf16*)(ws + 35239936);   // 65536x512 bf16
  bf16* hidden = qkv;                      // 65536x1024 bf16 reuses qkv region

  cvt_weights<<<2816, 256, 0, stream>>>(Wq, Wkv, Wproj, W1, W2, wqkv, wprojb, w1b, w2b);
  ln_kernel<<<16384, 256, 0, stream>>>(x, n1g, n1b, hbuf);
  // qkv: [65536x512] = h1 @ WqkvT, K=256. NCG=8 -> 2048 blocks
  gemm_reg<0, 8, 2048><<<2048, 256, 0, stream>>>(hbuf, wqkv, qkv, nullptr, nullptr, 512);
  hipMemsetAsync(Sbuf, 0, 7168 + 229376, stream);
  lattn_kernel<<<dim3(128, 8), 256, 0, stream>>>(qkv, hbuf);
  ctx_kernel<<<dim3(56, 32), 256, 0, stream>>>(qkv, ctx, Sbuf);
  lout_kernel<<<dim3(56, 32), 256, 0, stream>>>(qkv, Sbuf, ctx, hbuf);
  // proj + residual: out f32 = attn @ WprojT + bproj + x. NCG=4 -> 1024 blocks
  gemm_reg<1, 4, 1024><<<1024, 256, 0, stream>>>(hbuf, wprojb, out, bproj, x, 256);
  ln_kernel<<<16384, 256, 0, stream>>>(out, n2g, n2b, hbuf);
  // mlp1: hidden bf16 = gelu(h2 @ W1T + b1). NCG=16 -> 4096 blocks
  gemm_reg<2, 16, 4096><<<4096, 256, 0, stream>>>(hbuf, w1b, hidden, b1, nullptr, 1024);
  // mlp2 + residual (in-place RMW): out += hidden @ W2T + b2. 1024 blocks
  gemm_mlp2<<<1024, 256, 0, stream>>>(hidden, w2b, out, b2);
}

// Round 9
// 374.447 us; speedup vs baseline: 1.5981x; 1.5981x over previous
//
#include <hip/hip_runtime.h>
#include <hip/hip_bf16.h>

typedef __bf16 bf16;
typedef __bf16 bf16x8 __attribute__((ext_vector_type(8)));
typedef float f32x4 __attribute__((ext_vector_type(4)));

__device__ __forceinline__ void gld16(const void* g, void* l) {
  __builtin_amdgcn_global_load_lds((const __attribute__((address_space(1))) void*)g,
                                   (__attribute__((address_space(3))) void*)l, 16, 0, 0);
}

// ---------------- weight fp32 -> bf16 convert ----------------
__global__ void cvt_weights(const float* __restrict__ wq, const float* __restrict__ wkv,
                            const float* __restrict__ wp, const float* __restrict__ w1,
                            const float* __restrict__ w2,
                            bf16* __restrict__ wqkv, bf16* __restrict__ wpb,
                            bf16* __restrict__ w1b, bf16* __restrict__ w2b) {
  int i = blockIdx.x * 256 + threadIdx.x;
  if (i < 65536) wqkv[i] = (bf16)wq[i];
  else if (i < 131072) wqkv[i] = (bf16)wkv[i - 65536];
  else if (i < 196608) wpb[i - 131072] = (bf16)wp[i - 131072];
  else if (i < 458752) w1b[i - 196608] = (bf16)w1[i - 196608];
  else if (i < 720896) w2b[i - 458752] = (bf16)w2[i - 458752];
}

// ---------------- LayerNorm (wave per row, rows of 256) ----------------
__launch_bounds__(256)
__global__ void ln_kernel(const float* __restrict__ x, const float* __restrict__ g,
                          const float* __restrict__ b, bf16* __restrict__ out) {
  const int row = blockIdx.x * 4 + (threadIdx.x >> 6);
  const int lane = threadIdx.x & 63;
  const float4 v = ((const float4*)(x + (long)row * 256))[lane];
  float s = v.x + v.y + v.z + v.w;
#pragma unroll
  for (int o = 1; o < 64; o <<= 1) s += __shfl_xor(s, o);
  const float mu = s * (1.f / 256.f);
  const float dx = v.x - mu, dy = v.y - mu, dz = v.z - mu, dw = v.w - mu;
  float q = dx * dx + dy * dy + dz * dz + dw * dw;
#pragma unroll
  for (int o = 1; o < 64; o <<= 1) q += __shfl_xor(q, o);
  const float rstd = rsqrtf(q * (1.f / 256.f) + 1e-5f);
  const float4 gg = ((const float4*)g)[lane];
  const float4 bb = ((const float4*)b)[lane];
  union { bf16 h[4]; uint2 u; } pk;
  pk.h[0] = (bf16)(dx * rstd * gg.x + bb.x);
  pk.h[1] = (bf16)(dy * rstd * gg.y + bb.y);
  pk.h[2] = (bf16)(dz * rstd * gg.z + bb.z);
  pk.h[3] = (bf16)(dw * rstd * gg.w + bb.w);
  *(uint2*)(out + (long)row * 256 + lane * 4) = pk.u;
}

// ---------------- persistent-B pipelined GEMM (K=256 cases; R5-proven) ----------------
template <int EPI, int NCG, int NCHUNK, int THREADS, int MSPLIT>
__launch_bounds__(THREADS, 4)
__global__ void gemm_pb(const bf16* __restrict__ A, const bf16* __restrict__ Bw,
                        void* C, const float* __restrict__ bias,
                        const float* res, int ldC) {
  constexpr int WAVES = THREADS / 64;
  constexpr int WR = 2;
  constexpr int WC = WAVES / WR;
  constexpr int FN = 2;
  constexpr int FM = 64 / WR / 16;
  constexpr int COLS = WC * FN * 16;
  constexpr int KK = NCHUNK * 128;
  constexpr int ITER = 64 * 128 * 2 / (THREADS * 16);
  constexpr int TILES = 65536 / MSPLIT / 64;
  constexpr int CHB = 64 * 128 * 2;
  constexpr int BSZ = (EPI == 1) ? 64 * COLS * 4 : 64 * COLS * 2;
  constexpr int NST = (EPI == 1) ? 12 : 2;
  constexpr int NBLK = NCG * MSPLIT;
  __shared__ char smem[3 * CHB + BSZ];
  const int tid = threadIdx.x;
  const int w = tid >> 6, lane = tid & 63;
  const int l15 = lane & 15, l4 = lane >> 4;
  const int wrow = w & (WR - 1), wcol = w / WR;
  const int bid = blockIdx.x;
  const int slot = (bid & 7) * (NBLK / 8) + (bid >> 3);
  const int cg = slot % NCG;
  const long strip0 = (long)(slot / NCG) * (65536 / MSPLIT);

  const bf16* Bl = Bw + (long)(cg * COLS + wcol * FN * 16 + l15) * KK + l4 * 8;
  bf16x8 Breg[NCHUNK][4][FN];
#pragma unroll
  for (int c = 0; c < NCHUNK; ++c)
#pragma unroll
    for (int kl = 0; kl < 4; ++kl)
#pragma unroll
      for (int fn = 0; fn < FN; ++fn)
        Breg[c][kl][fn] = *(const bf16x8*)(Bl + (long)fn * 16 * KK + c * 128 + kl * 32);

  float bias_r[FN];
  if constexpr (EPI == 2) {
#pragma unroll
    for (int fn = 0; fn < FN; ++fn)
      bias_r[fn] = bias[cg * COLS + wcol * FN * 16 + fn * 16 + l15];
  }
  asm volatile("" ::: "memory");   // pin Breg/bias loads in the prologue

  auto stage = [&](int m, int c, int buf) {
#pragma unroll
    for (int it = 0; it < ITER; ++it) {
      const int p = it * (THREADS * 16) + tid * 16;
      const int row = p >> 8;
      const int colb = (p & 255) ^ ((row & 7) << 4);
      gld16((const char*)A + ((strip0 + m * 64 + row) * KK + c * 128) * 2 + colb,
            smem + buf * CHB + it * (THREADS * 16) + w * 1024);
    }
  };

  f32x4 acc[FM][FN] = {};
  stage(0, 0, 0);
  stage(0, 1, 1);

  for (int m = 0; m < TILES; ++m) {
#pragma unroll
    for (int c = 0; c < NCHUNK; ++c) {
      const int s = m * NCHUNK + c;
      if (m == 0 || c >= 2) {
        asm volatile("s_waitcnt vmcnt(%0)" ::"i"(ITER) : "memory");
      } else {
        asm volatile("s_waitcnt vmcnt(%0)" ::"i"(ITER + NST) : "memory");
      }
      __syncthreads();
      {
        int c2 = c + 2, m2 = m;
        if (c2 >= NCHUNK) { c2 -= NCHUNK; ++m2; }
        if (m2 < TILES) stage(m2, c2, (s + 2) % 3);
      }
      const char* Ab = smem + (s % 3) * CHB;
#pragma unroll
      for (int kl = 0; kl < 4; ++kl) {
        bf16x8 af[FM];
#pragma unroll
        for (int fm = 0; fm < FM; ++fm) {
          const int arow = wrow * (64 / WR) + fm * 16 + l15;
          af[fm] = *(const bf16x8*)(Ab + arow * 256 + ((kl * 64 + l4 * 16) ^ ((l15 & 7) << 4)));
        }
#pragma unroll
        for (int fm = 0; fm < FM; ++fm)
#pragma unroll
          for (int fn = 0; fn < FN; ++fn)
            acc[fm][fn] = __builtin_amdgcn_mfma_f32_16x16x32_bf16(af[fm], Breg[c][kl][fn],
                                                                  acc[fm][fn], 0, 0, 0);
      }
      if (c == NCHUNK - 1) {
        if constexpr (EPI == 1) {
          float* fb = (float*)(smem + 3 * CHB);
#pragma unroll
          for (int fm = 0; fm < FM; ++fm)
#pragma unroll
            for (int fn = 0; fn < FN; ++fn)
#pragma unroll
              for (int r = 0; r < 4; ++r)
                fb[(wrow * (64 / WR) + fm * 16 + l4 * 4 + r) * COLS +
                   wcol * FN * 16 + fn * 16 + l15] = acc[fm][fn][r];
          __syncthreads();
#pragma unroll
          for (int it = 0; it < 64 * COLS * 4 / (THREADS * 16); ++it) {
            const int off = it * (THREADS * 16) + tid * 16;
            const int row = off / (COLS * 4);
            const int colb = off % (COLS * 4);
            const long gb = ((strip0 + m * 64 + row) * ldC + cg * COLS) * 4 + colb;
            float4 v = *(const float4*)(smem + 3 * CHB + off);
            const float4 rr = *(const float4*)((const char*)res + gb);
            const float4 bv = *(const float4*)((const char*)bias + cg * COLS * 4 + colb);
            v.x += rr.x + bv.x; v.y += rr.y + bv.y;
            v.z += rr.z + bv.z; v.w += rr.w + bv.w;
            *(float4*)((char*)C + gb) = v;
          }
        } else {
          bf16* bb = (bf16*)(smem + 3 * CHB);
#pragma unroll
          for (int fm = 0; fm < FM; ++fm)
#pragma unroll
            for (int fn = 0; fn < FN; ++fn)
#pragma unroll
              for (int r = 0; r < 4; ++r) {
                float v = acc[fm][fn][r];
                if constexpr (EPI == 2) {
                  v += bias_r[fn];
                  v = 0.5f * v * (1.f + erff(v * 0.70710678118654752f));
                }
                bb[(wrow * (64 / WR) + fm * 16 + l4 * 4 + r) * COLS +
                   wcol * FN * 16 + fn * 16 + l15] = (bf16)v;
              }
          __syncthreads();
#pragma unroll
          for (int it = 0; it < 64 * COLS * 2 / (THREADS * 16); ++it) {
            const int off = it * (THREADS * 16) + tid * 16;
            const int row = off / (COLS * 2);
            const int colb = off % (COLS * 2);
            *(uint4*)((char*)C + ((strip0 + m * 64 + row) * ldC + cg * COLS) * 2 + colb) =
                *(const uint4*)(smem + 3 * CHB + off);
          }
        }
#pragma unroll
        for (int fm = 0; fm < FM; ++fm)
#pragma unroll
          for (int fn = 0; fn < FN; ++fn)
            acc[fm][fn] = f32x4{0.f, 0.f, 0.f, 0.f};
      }
    }
  }
}

// ---------------- mlp2: split-K=2 persistent-B GEMM, atomic epilogue ----------------
// out[65536x256] += hidden[:, kh*512:+512] @ W2[:, kh*512:+512]^T (+ b2 on kh==0).
// 512 thr, block tile 64x128, NCHUNK=4 (K=512 per half), Breg[4][4][2]=128 VGPR persistent
// under the (512,2) cap of 256. 3-buffer LDS A-pipeline, counted vmcnt (2 steady / 18
// post-epilogue), fire-and-forget atomicAdd epilogue (out holds x2 residual from proj).
__launch_bounds__(512, 2)
__global__ void gemm_mlp2(const bf16* __restrict__ A, const bf16* __restrict__ Bw,
                          float* __restrict__ C, const float* __restrict__ bias) {
  constexpr int ITER = 2, NCHUNK = 4, TILES = 4, CHB = 64 * 128 * 2;
  __shared__ char smem[3 * CHB];
  const int tid = threadIdx.x;
  const int w = tid >> 6, lane = tid & 63;
  const int l15 = lane & 15, l4 = lane >> 4;
  const int wrow = w & 1, wcol = w >> 1;
  const int kh = blockIdx.y;                       // K-half
  const int bid = blockIdx.x;                      // 512
  const int slot = (bid & 7) * 64 + (bid >> 3);    // bijective XCD swizzle
  const int cg = slot & 1;                         // cg-siblings adjacent -> A-strip L2 reuse
  const long strip0 = (long)(slot >> 1) * 256;

  const bf16* Bl = Bw + (long)(cg * 128 + wcol * 32 + l15) * 1024 + kh * 512 + l4 * 8;
  bf16x8 Breg[NCHUNK][4][2];
#pragma unroll
  for (int c = 0; c < NCHUNK; ++c)
#pragma unroll
    for (int kl = 0; kl < 4; ++kl)
#pragma unroll
      for (int fn = 0; fn < 2; ++fn)
        Breg[c][kl][fn] = *(const bf16x8*)(Bl + (long)fn * 16 * 1024 + c * 128 + kl * 32);
  float biasr[2];
#pragma unroll
  for (int fn = 0; fn < 2; ++fn)
    biasr[fn] = kh ? 0.f : bias[cg * 128 + wcol * 32 + fn * 16 + l15];
  asm volatile("" ::: "memory");   // pin Breg/bias loads in the prologue

  auto stage = [&](int m, int c, int buf) {
#pragma unroll
    for (int it = 0; it < ITER; ++it) {
      const int p = it * 8192 + tid * 16;
      const int row = p >> 8;
      const int colb = (p & 255) ^ ((row & 7) << 4);
      gld16((const char*)A + (((strip0 + m * 64 + row) * 1024) + kh * 512 + c * 128) * 2 + colb,
            smem + buf * CHB + it * 8192 + w * 1024);
    }
  };

  f32x4 acc[2][2] = {};
  stage(0, 0, 0);
  stage(0, 1, 1);

  for (int m = 0; m < TILES; ++m) {
#pragma unroll
    for (int c = 0; c < NCHUNK; ++c) {
      const int s = m * NCHUNK + c;
      if (m == 0 || c >= 2) {
        asm volatile("s_waitcnt vmcnt(2)" ::: "memory");
      } else {
        asm volatile("s_waitcnt vmcnt(18)" ::: "memory");   // 16 epilogue atomics + 2 stage
      }
      __syncthreads();
      {
        int c2 = c + 2, m2 = m;
        if (c2 >= NCHUNK) { c2 -= NCHUNK; ++m2; }
        if (m2 < TILES) stage(m2, c2, (s + 2) % 3);
      }
      const char* Ab = smem + (s % 3) * CHB;
#pragma unroll
      for (int kl = 0; kl < 4; ++kl) {
        bf16x8 af[2];
#pragma unroll
        for (int fm = 0; fm < 2; ++fm) {
          const int arow = wrow * 32 + fm * 16 + l15;
          af[fm] = *(const bf16x8*)(Ab + arow * 256 + ((kl * 64 + l4 * 16) ^ ((l15 & 7) << 4)));
        }
#pragma unroll
        for (int fm = 0; fm < 2; ++fm)
#pragma unroll
          for (int fn = 0; fn < 2; ++fn)
            acc[fm][fn] = __builtin_amdgcn_mfma_f32_16x16x32_bf16(af[fm], Breg[c][kl][fn],
                                                                  acc[fm][fn], 0, 0, 0);
      }
      if (c == NCHUNK - 1) {
        // fire-and-forget atomic epilogue: no loads, no waits
#pragma unroll
        for (int fm = 0; fm < 2; ++fm)
#pragma unroll
          for (int fn = 0; fn < 2; ++fn)
#pragma unroll
            for (int r = 0; r < 4; ++r) {
              const long row = strip0 + m * 64 + wrow * 32 + fm * 16 + l4 * 4 + r;
              const long idx = row * 256 + cg * 128 + wcol * 32 + fn * 16 + l15;
              atomicAdd(&C[idx], acc[fm][fn][r] + biasr[fn]);
              acc[fm][fn][r] = 0.f;
            }
      }
    }
  }
}

// ---------------- local window attention (head 0), one block per (window, batch) ----------------
__launch_bounds__(256)
__global__ void lattn_kernel(const bf16* __restrict__ qkv, bf16* __restrict__ attn) {
  const int j = blockIdx.x, b = blockIdx.y;
  const int tid = threadIdx.x, w = tid >> 6, lane = tid & 63;
  __shared__ bf16 Qs[64 * 40];
  __shared__ bf16 Ks[192 * 40];
  __shared__ bf16 Kt[32 * 200];
  __shared__ bf16 Ps[4][16 * 200];
  const float scale = 0.17677669529663687f;
  const long base = (long)b * 8192 + (long)j * 64;
  for (int i = tid; i < 64 * 32; i += 256) {
    const int r = i >> 5, d = i & 31;
    Qs[r * 40 + d] = (bf16)((float)qkv[(base + r) * 512 + d] * scale);
  }
  for (int i = tid; i < 192 * 32; i += 256) {
    const int c = i >> 5, d = i & 31;
    const long tc = (long)j * 64 - 64 + c;
    float kv = 0.f;
    if (tc >= 0 && tc < 8192) kv = (float)qkv[((long)b * 8192 + tc) * 512 + 256 + d];
    const bf16 kb = (bf16)kv;
    Ks[c * 40 + d] = kb;
    Kt[d * 200 + c] = kb;
  }
  __syncthreads();
  const int l15 = lane & 15, l4 = lane >> 4;
  const bf16x8 aq = *(const bf16x8*)(Qs + (w * 16 + l15) * 40 + l4 * 8);
  const f32x4 zz = {0.f, 0.f, 0.f, 0.f};
  f32x4 S[12];
#pragma unroll
  for (int fn = 0; fn < 12; ++fn) {
    const bf16x8 bk = *(const bf16x8*)(Ks + (fn * 16 + l15) * 40 + l4 * 8);
    S[fn] = __builtin_amdgcn_mfma_f32_16x16x32_bf16(aq, bk, zz, 0, 0, 0);
  }
#pragma unroll
  for (int fn = 0; fn < 12; ++fn) {
    const long tc = (long)j * 64 - 64 + fn * 16 + l15;
    if (tc < 0 || tc >= 8192) { S[fn][0] = -1e9f; S[fn][1] = -1e9f; S[fn][2] = -1e9f; S[fn][3] = -1e9f; }
  }
  float sinv[4];
#pragma unroll
  for (int r = 0; r < 4; ++r) {
    float m = -1e30f;
#pragma unroll
    for (int fn = 0; fn < 12; ++fn) m = fmaxf(m, S[fn][r]);
#pragma unroll
    for (int o = 1; o < 16; o <<= 1) m = fmaxf(m, __shfl_xor(m, o));
    float s = 0.f;
#pragma unroll
    for (int fn = 0; fn < 12; ++fn) { const float e = __expf(S[fn][r] - m); S[fn][r] = e; s += e; }
#pragma unroll
    for (int o = 1; o < 16; o <<= 1) s += __shfl_xor(s, o);
    sinv[r] = 1.f / s;
  }
#pragma unroll
  for (int fn = 0; fn < 12; ++fn)
#pragma unroll
    for (int r = 0; r < 4; ++r)
      Ps[w][(l4 * 4 + r) * 200 + fn * 16 + l15] = (bf16)(S[fn][r] * sinv[r]);
  __syncthreads();
  f32x4 O[2] = {};
#pragma unroll
  for (int ks = 0; ks < 6; ++ks) {
    const bf16x8 ap = *(const bf16x8*)(Ps[w] + l15 * 200 + ks * 32 + l4 * 8);
#pragma unroll
    for (int fe = 0; fe < 2; ++fe) {
      const bf16x8 bv = *(const bf16x8*)(Kt + (fe * 16 + l15) * 200 + ks * 32 + l4 * 8);
      O[fe] = __builtin_amdgcn_mfma_f32_16x16x32_bf16(ap, bv, O[fe], 0, 0, 0);
    }
  }
#pragma unroll
  for (int fe = 0; fe < 2; ++fe)
#pragma unroll
    for (int r = 0; r < 4; ++r)
      attn[(base + w * 16 + l4 * 4 + r) * 256 + fe * 16 + l15] = (bf16)O[fe][r];
}

// ---------------- linear attn ctx via MFMA (S via ones-row) ----------------
__launch_bounds__(256)
__global__ void ctx_kernel(const bf16* __restrict__ qkv, float* __restrict__ ctx,
                           float* __restrict__ S) {
  const int bh = blockIdx.x;
  const int b = bh / 7, h = bh % 7 + 1;
  const int tid = threadIdx.x;
  const int w = tid >> 6, lane = tid & 63;
  const int l15 = lane & 15, l4 = lane >> 4;
  __shared__ bf16 evT[32 * 264];
  __shared__ bf16 kT[48 * 264];
  __shared__ float red[4][32 * 48];
  const long n0 = (long)blockIdx.y * 256;
  const bf16* kp = qkv + ((long)b * 8192 + n0 + tid) * 512 + 256 + h * 32;
  bf16x8 kv[4];
#pragma unroll
  for (int c = 0; c < 4; ++c) kv[c] = *(const bf16x8*)(kp + c * 8);
#pragma unroll
  for (int i = 0; i < 16; ++i)
    kT[(32 + i) * 264 + tid] = (i == 0) ? (bf16)1.0f : (bf16)0.0f;
#pragma unroll
  for (int c = 0; c < 4; ++c)
#pragma unroll
    for (int j = 0; j < 8; ++j) {
      const int d = c * 8 + j;
      evT[d * 264 + tid] = (bf16)__expf((float)kv[c][j]);
      kT[d * 264 + tid] = kv[c][j];
    }
  __syncthreads();
  f32x4 acc[2][3] = {};
#pragma unroll
  for (int ks = 0; ks < 2; ++ks) {
    const int ncol = w * 64 + ks * 32 + l4 * 8;
    bf16x8 af[2], bb[3];
#pragma unroll
    for (int fm = 0; fm < 2; ++fm) af[fm] = *(const bf16x8*)(evT + (fm * 16 + l15) * 264 + ncol);
#pragma unroll
    for (int fe = 0; fe < 3; ++fe) bb[fe] = *(const bf16x8*)(kT + (fe * 16 + l15) * 264 + ncol);
#pragma unroll
    for (int fm = 0; fm < 2; ++fm)
#pragma unroll
      for (int fe = 0; fe < 3; ++fe)
        acc[fm][fe] = __builtin_amdgcn_mfma_f32_16x16x32_bf16(af[fm], bb[fe], acc[fm][fe], 0, 0, 0);
  }
#pragma unroll
  for (int fm = 0; fm < 2; ++fm)
#pragma unroll
    for (int fe = 0; fe < 3; ++fe)
#pragma unroll
      for (int r = 0; r < 4; ++r)
        red[w][(fm * 16 + l4 * 4 + r) * 48 + fe * 16 + l15] = acc[fm][fe][r];
  __syncthreads();
  for (int i = tid; i < 32 * 48; i += 256) {
    const float v = red[0][i] + red[1][i] + red[2][i] + red[3][i];
    const int d = i / 48, e = i - d * 48;
    if (e < 32) atomicAdd(ctx + (long)bh * 1024 + d * 32 + e, v);
    else if (e == 32) atomicAdd(S + bh * 32 + d, v);
  }
}

// ---------------- linear attn out via register softmax + MFMA ----------------
__launch_bounds__(256)
__global__ void lout_kernel(const bf16* __restrict__ qkv, const float* __restrict__ S,
                            const float* __restrict__ ctx, bf16* __restrict__ attn) {
  const int bh = blockIdx.x;
  const int b = bh / 7, h = bh % 7 + 1;
  const int tid = threadIdx.x;
  const int w = tid >> 6, lane = tid & 63;
  const int l15 = lane & 15, l4 = lane >> 4;
  __shared__ bf16 qs[256 * 40];
  __shared__ bf16 C2t[32 * 40];
  const long n0 = (long)blockIdx.y * 256;
  for (int i = tid; i < 1024; i += 256) {
    const int e = i >> 5, d = i & 31;
    C2t[e * 40 + d] = (bf16)(ctx[(long)bh * 1024 + d * 32 + e] / S[bh * 32 + d]);
  }
  const bf16* qp = qkv + ((long)b * 8192 + n0 + tid) * 512 + h * 32;
  bf16x8 qv[4];
#pragma unroll
  for (int c = 0; c < 4; ++c) qv[c] = *(const bf16x8*)(qp + c * 8);
  float qf[32];
#pragma unroll
  for (int c = 0; c < 4; ++c)
#pragma unroll
    for (int j = 0; j < 8; ++j) qf[c * 8 + j] = (float)qv[c][j];
  float m = qf[0];
#pragma unroll
  for (int d = 1; d < 32; ++d) m = fmaxf(m, qf[d]);
  float s = 0.f;
#pragma unroll
  for (int d = 0; d < 32; ++d) { qf[d] = __expf(qf[d] - m); s += qf[d]; }
  const float f = 0.17677669529663687f / s;
#pragma unroll
  for (int c = 0; c < 4; ++c) {
    bf16x8 o;
#pragma unroll
    for (int j = 0; j < 8; ++j) o[j] = (bf16)(qf[c * 8 + j] * f);
    *(bf16x8*)(qs + tid * 40 + c * 8) = o;
  }
  __syncthreads();
  f32x4 acc[4][2] = {};
  bf16x8 bfr[2];
#pragma unroll
  for (int fe = 0; fe < 2; ++fe) bfr[fe] = *(const bf16x8*)(C2t + (fe * 16 + l15) * 40 + l4 * 8);
#pragma unroll
  for (int fm = 0; fm < 4; ++fm) {
    const bf16x8 af = *(const bf16x8*)(qs + (w * 64 + fm * 16 + l15) * 40 + l4 * 8);
#pragma unroll
    for (int fe = 0; fe < 2; ++fe)
      acc[fm][fe] = __builtin_amdgcn_mfma_f32_16x16x32_bf16(af, bfr[fe], acc[fm][fe], 0, 0, 0);
  }
#pragma unroll
  for (int fm = 0; fm < 4; ++fm)
#pragma unroll
    for (int fe = 0; fe < 2; ++fe)
#pragma unroll
      for (int r = 0; r < 4; ++r)
        attn[((long)b * 8192 + n0 + w * 64 + fm * 16 + l4 * 4 + r) * 256 + h * 32 + fe * 16 + l15]
            = (bf16)acc[fm][fe][r];
}

extern "C" void kernel_launch(void* const* d_in, const int* in_sizes, int n_in,
                              void* d_out, int out_size, void* d_ws, size_t ws_size,
                              hipStream_t stream) {
  const float* x     = (const float*)d_in[0];
  const float* n1g   = (const float*)d_in[1];
  const float* n1b   = (const float*)d_in[2];
  const float* Wq    = (const float*)d_in[3];
  const float* Wkv   = (const float*)d_in[4];
  const float* Wproj = (const float*)d_in[5];
  const float* bproj = (const float*)d_in[6];
  const float* n2g   = (const float*)d_in[7];
  const float* n2b   = (const float*)d_in[8];
  const float* W1    = (const float*)d_in[9];
  const float* b1    = (const float*)d_in[10];
  const float* W2    = (const float*)d_in[11];
  const float* b2    = (const float*)d_in[12];
  float* out = (float*)d_out;
  char* ws = (char*)d_ws;

  bf16* wqkv   = (bf16*)(ws + 0);
  bf16* wprojb = (bf16*)(ws + 262144);
  bf16* w1b    = (bf16*)(ws + 393216);
  bf16* w2b    = (bf16*)(ws + 917504);
  float* Sbuf  = (float*)(ws + 1441792);   // 56*32 f32, contiguous with ctx for one memset
  float* ctx   = (float*)(ws + 1448960);   // 56*1024 f32
  bf16* hbuf   = (bf16*)(ws + 1685504);    // 65536x256 bf16 (h1 -> attn -> h2)
  bf16* qkv    = (bf16*)(ws + 35239936);   // 65536x512 bf16
  bf16* hidden = qkv;                      // 65536x1024 bf16 reuses qkv region

  cvt_weights<<<2816, 256, 0, stream>>>(Wq, Wkv, Wproj, W1, W2, wqkv, wprojb, w1b, w2b);
  ln_kernel<<<16384, 256, 0, stream>>>(x, n1g, n1b, hbuf);
  // qkv: [65536x512] = h1 @ WqkvT, K=256. NCG=4, MSPLIT=128 -> 512 blocks
  gemm_pb<0, 4, 2, 512, 128><<<512, 512, 0, stream>>>(hbuf, wqkv, qkv, nullptr, nullptr, 512);
  hipMemsetAsync(Sbuf, 0, 7168 + 229376, stream);
  lattn_kernel<<<dim3(128, 8), 256, 0, stream>>>(qkv, hbuf);
  ctx_kernel<<<dim3(56, 32), 256, 0, stream>>>(qkv, ctx, Sbuf);
  lout_kernel<<<dim3(56, 32), 256, 0, stream>>>(qkv, Sbuf, ctx, hbuf);
  // proj + residual: out f32 = attn @ WprojT + bproj + x. NCG=2, MSPLIT=256 -> 512 blocks
  gemm_pb<1, 2, 2, 512, 256><<<512, 512, 0, stream>>>(hbuf, wprojb, out, bproj, x, 256);
  ln_kernel<<<16384, 256, 0, stream>>>(out, n2g, n2b, hbuf);
  // mlp1: hidden bf16 = gelu(h2 @ W1T + b1). NCG=8, MSPLIT=64 -> 512 blocks
  gemm_pb<2, 8, 2, 512, 64><<<512, 512, 0, stream>>>(hbuf, w1b, hidden, b1, nullptr, 1024);
  // mlp2 + residual (split-K=2, atomic): out += hidden @ W2T + b2. dim3(512,2) x 512 thr
  gemm_mlp2<<<dim3(512, 2), 512, 0, stream>>>(hidden, w2b, out, b2);
}

// Round 10
// 365.765 us; speedup vs baseline: 1.6361x; 1.0237x over previous
//
#include <hip/hip_runtime.h>
#include <hip/hip_bf16.h>

typedef __bf16 bf16;
typedef __bf16 bf16x8 __attribute__((ext_vector_type(8)));
typedef float f32x4 __attribute__((ext_vector_type(4)));

__device__ __forceinline__ void gld16(const void* g, void* l) {
  __builtin_amdgcn_global_load_lds((const __attribute__((address_space(1))) void*)g,
                                   (__attribute__((address_space(3))) void*)l, 16, 0, 0);
}

// ---------------- weight fp32 -> bf16 convert ----------------
__global__ void cvt_weights(const float* __restrict__ wq, const float* __restrict__ wkv,
                            const float* __restrict__ wp, const float* __restrict__ w1,
                            const float* __restrict__ w2,
                            bf16* __restrict__ wqkv, bf16* __restrict__ wpb,
                            bf16* __restrict__ w1b, bf16* __restrict__ w2b) {
  int i = blockIdx.x * 256 + threadIdx.x;
  if (i < 65536) wqkv[i] = (bf16)wq[i];
  else if (i < 131072) wqkv[i] = (bf16)wkv[i - 65536];
  else if (i < 196608) wpb[i - 131072] = (bf16)wp[i - 131072];
  else if (i < 458752) w1b[i - 196608] = (bf16)w1[i - 196608];
  else if (i < 720896) w2b[i - 458752] = (bf16)w2[i - 458752];
}

// ---------------- LayerNorm (wave per row, rows of 256) ----------------
__launch_bounds__(256)
__global__ void ln_kernel(const float* __restrict__ x, const float* __restrict__ g,
                          const float* __restrict__ b, bf16* __restrict__ out) {
  const int row = blockIdx.x * 4 + (threadIdx.x >> 6);
  const int lane = threadIdx.x & 63;
  const float4 v = ((const float4*)(x + (long)row * 256))[lane];
  float s = v.x + v.y + v.z + v.w;
#pragma unroll
  for (int o = 1; o < 64; o <<= 1) s += __shfl_xor(s, o);
  const float mu = s * (1.f / 256.f);
  const float dx = v.x - mu, dy = v.y - mu, dz = v.z - mu, dw = v.w - mu;
  float q = dx * dx + dy * dy + dz * dz + dw * dw;
#pragma unroll
  for (int o = 1; o < 64; o <<= 1) q += __shfl_xor(q, o);
  const float rstd = rsqrtf(q * (1.f / 256.f) + 1e-5f);
  const float4 gg = ((const float4*)g)[lane];
  const float4 bb = ((const float4*)b)[lane];
  union { bf16 h[4]; uint2 u; } pk;
  pk.h[0] = (bf16)(dx * rstd * gg.x + bb.x);
  pk.h[1] = (bf16)(dy * rstd * gg.y + bb.y);
  pk.h[2] = (bf16)(dz * rstd * gg.z + bb.z);
  pk.h[3] = (bf16)(dw * rstd * gg.w + bb.w);
  *(uint2*)(out + (long)row * 256 + lane * 4) = pk.u;
}

// ---------------- persistent-B pipelined GEMM (K=256 cases; R5-proven) ----------------
template <int EPI, int NCG, int NCHUNK, int THREADS, int MSPLIT>
__launch_bounds__(THREADS, 4)
__global__ void gemm_pb(const bf16* __restrict__ A, const bf16* __restrict__ Bw,
                        void* C, const float* __restrict__ bias,
                        const float* res, int ldC) {
  constexpr int WAVES = THREADS / 64;
  constexpr int WR = 2;
  constexpr int WC = WAVES / WR;
  constexpr int FN = 2;
  constexpr int FM = 64 / WR / 16;
  constexpr int COLS = WC * FN * 16;
  constexpr int KK = NCHUNK * 128;
  constexpr int ITER = 64 * 128 * 2 / (THREADS * 16);
  constexpr int TILES = 65536 / MSPLIT / 64;
  constexpr int CHB = 64 * 128 * 2;
  constexpr int BSZ = (EPI == 1) ? 64 * COLS * 4 : 64 * COLS * 2;
  constexpr int NST = (EPI == 1) ? 12 : 2;
  constexpr int NBLK = NCG * MSPLIT;
  __shared__ char smem[3 * CHB + BSZ];
  const int tid = threadIdx.x;
  const int w = tid >> 6, lane = tid & 63;
  const int l15 = lane & 15, l4 = lane >> 4;
  const int wrow = w & (WR - 1), wcol = w / WR;
  const int bid = blockIdx.x;
  const int slot = (bid & 7) * (NBLK / 8) + (bid >> 3);
  const int cg = slot % NCG;
  const long strip0 = (long)(slot / NCG) * (65536 / MSPLIT);

  const bf16* Bl = Bw + (long)(cg * COLS + wcol * FN * 16 + l15) * KK + l4 * 8;
  bf16x8 Breg[NCHUNK][4][FN];
#pragma unroll
  for (int c = 0; c < NCHUNK; ++c)
#pragma unroll
    for (int kl = 0; kl < 4; ++kl)
#pragma unroll
      for (int fn = 0; fn < FN; ++fn)
        Breg[c][kl][fn] = *(const bf16x8*)(Bl + (long)fn * 16 * KK + c * 128 + kl * 32);

  float bias_r[FN];
  if constexpr (EPI == 2) {
#pragma unroll
    for (int fn = 0; fn < FN; ++fn)
      bias_r[fn] = bias[cg * COLS + wcol * FN * 16 + fn * 16 + l15];
  }
  asm volatile("" ::: "memory");   // pin Breg/bias loads in the prologue

  auto stage = [&](int m, int c, int buf) {
#pragma unroll
    for (int it = 0; it < ITER; ++it) {
      const int p = it * (THREADS * 16) + tid * 16;
      const int row = p >> 8;
      const int colb = (p & 255) ^ ((row & 7) << 4);
      gld16((const char*)A + ((strip0 + m * 64 + row) * KK + c * 128) * 2 + colb,
            smem + buf * CHB + it * (THREADS * 16) + w * 1024);
    }
  };

  f32x4 acc[FM][FN] = {};
  stage(0, 0, 0);
  stage(0, 1, 1);

  for (int m = 0; m < TILES; ++m) {
#pragma unroll
    for (int c = 0; c < NCHUNK; ++c) {
      const int s = m * NCHUNK + c;
      if (m == 0 || c >= 2) {
        asm volatile("s_waitcnt vmcnt(%0)" ::"i"(ITER) : "memory");
      } else {
        asm volatile("s_waitcnt vmcnt(%0)" ::"i"(ITER + NST) : "memory");
      }
      __syncthreads();
      {
        int c2 = c + 2, m2 = m;
        if (c2 >= NCHUNK) { c2 -= NCHUNK; ++m2; }
        if (m2 < TILES) stage(m2, c2, (s + 2) % 3);
      }
      const char* Ab = smem + (s % 3) * CHB;
#pragma unroll
      for (int kl = 0; kl < 4; ++kl) {
        bf16x8 af[FM];
#pragma unroll
        for (int fm = 0; fm < FM; ++fm) {
          const int arow = wrow * (64 / WR) + fm * 16 + l15;
          af[fm] = *(const bf16x8*)(Ab + arow * 256 + ((kl * 64 + l4 * 16) ^ ((l15 & 7) << 4)));
        }
#pragma unroll
        for (int fm = 0; fm < FM; ++fm)
#pragma unroll
          for (int fn = 0; fn < FN; ++fn)
            acc[fm][fn] = __builtin_amdgcn_mfma_f32_16x16x32_bf16(af[fm], Breg[c][kl][fn],
                                                                  acc[fm][fn], 0, 0, 0);
      }
      if (c == NCHUNK - 1) {
        if constexpr (EPI == 1) {
          float* fb = (float*)(smem + 3 * CHB);
#pragma unroll
          for (int fm = 0; fm < FM; ++fm)
#pragma unroll
            for (int fn = 0; fn < FN; ++fn)
#pragma unroll
              for (int r = 0; r < 4; ++r)
                fb[(wrow * (64 / WR) + fm * 16 + l4 * 4 + r) * COLS +
                   wcol * FN * 16 + fn * 16 + l15] = acc[fm][fn][r];
          __syncthreads();
#pragma unroll
          for (int it = 0; it < 64 * COLS * 4 / (THREADS * 16); ++it) {
            const int off = it * (THREADS * 16) + tid * 16;
            const int row = off / (COLS * 4);
            const int colb = off % (COLS * 4);
            const long gb = ((strip0 + m * 64 + row) * ldC + cg * COLS) * 4 + colb;
            float4 v = *(const float4*)(smem + 3 * CHB + off);
            const float4 rr = *(const float4*)((const char*)res + gb);
            const float4 bv = *(const float4*)((const char*)bias + cg * COLS * 4 + colb);
            v.x += rr.x + bv.x; v.y += rr.y + bv.y;
            v.z += rr.z + bv.z; v.w += rr.w + bv.w;
            *(float4*)((char*)C + gb) = v;
          }
        } else {
          bf16* bb = (bf16*)(smem + 3 * CHB);
#pragma unroll
          for (int fm = 0; fm < FM; ++fm)
#pragma unroll
            for (int fn = 0; fn < FN; ++fn)
#pragma unroll
              for (int r = 0; r < 4; ++r) {
                float v = acc[fm][fn][r];
                if constexpr (EPI == 2) {
                  v += bias_r[fn];
                  v = 0.5f * v * (1.f + erff(v * 0.70710678118654752f));
                }
                bb[(wrow * (64 / WR) + fm * 16 + l4 * 4 + r) * COLS +
                   wcol * FN * 16 + fn * 16 + l15] = (bf16)v;
              }
          __syncthreads();
#pragma unroll
          for (int it = 0; it < 64 * COLS * 2 / (THREADS * 16); ++it) {
            const int off = it * (THREADS * 16) + tid * 16;
            const int row = off / (COLS * 2);
            const int colb = off % (COLS * 2);
            *(uint4*)((char*)C + ((strip0 + m * 64 + row) * ldC + cg * COLS) * 2 + colb) =
                *(const uint4*)(smem + 3 * CHB + off);
          }
        }
#pragma unroll
        for (int fm = 0; fm < FM; ++fm)
#pragma unroll
          for (int fn = 0; fn < FN; ++fn)
            acc[fm][fn] = f32x4{0.f, 0.f, 0.f, 0.f};
      }
    }
  }
}

// ---------------- mlp2 v3: high-occupancy FIFO pipeline (6 blocks/CU) ----------------
// out[65536x256] += hidden @ W2^T + b2 (out holds x2 residual). 2048 blocks x 256 thr.
// Chunk = 64 rows x 64 K (8KB); 3 buffers = 24KB LDS -> 6 blocks/CU at (256,6).
// Per chunk: wait vmcnt(6) [B(c)4 + stage(c+1)2 outstanding] -> barrier -> loadB(c+1)
// -> stage(c+2) -> MFMA. B in two named 16-VGPR sets (<=64-VGPR residency law).
// Atomic fire-and-forget epilogue, no waits.
__launch_bounds__(256, 6)
__global__ void gemm_mlp2(const bf16* __restrict__ A, const bf16* __restrict__ Bw,
                          float* __restrict__ C, const float* __restrict__ bias) {
  constexpr int CHB = 64 * 64 * 2;   // 8KB chunk
  __shared__ char smem[3 * CHB];
  const int tid = threadIdx.x;
  const int w = tid >> 6, lane = tid & 63;
  const int l15 = lane & 15, l4 = lane >> 4;
  const int bid = blockIdx.x;                      // 2048 blocks
  const int slot = (bid & 7) * 256 + (bid >> 3);   // bijective XCD swizzle
  const int cg = slot & 1;                         // cg-siblings adjacent -> A-strip L2 reuse
  const long strip0 = (long)(slot >> 1) * 64;
  const bf16* Bl = Bw + (long)(cg * 128 + w * 32 + l15) * 1024 + l4 * 8;
  const float bias0 = bias[cg * 128 + w * 32 + l15];
  const float bias1 = bias[cg * 128 + w * 32 + 16 + l15];
  asm volatile("" ::: "memory");

  auto stage = [&](int c, int buf) {
#pragma unroll
    for (int it = 0; it < 2; ++it) {
      const int p = it * 4096 + tid * 16;
      const int row = p >> 7;                          // 128B rows (64 K bf16)
      const int colb = (p & 127) ^ ((row & 7) << 4);   // inverse swizzle at source
      gld16((const char*)A + ((strip0 + row) * 1024 + c * 64) * 2 + colb,
            smem + buf * CHB + it * 4096 + w * 1024);
    }
  };
  auto loadB = [&](int c, bf16x8 (&Bn)[2][2]) {
#pragma unroll
    for (int fn = 0; fn < 2; ++fn)
#pragma unroll
      for (int kl = 0; kl < 2; ++kl)
        Bn[fn][kl] = *(const bf16x8*)(Bl + (long)fn * 16 * 1024 + c * 64 + kl * 32);
  };

  bf16x8 B0[2][2], B1[2][2];
  f32x4 acc[4][2] = {};
  // prologue FIFO order: stage0, B0, stage1 (B0's wait must not force stage1)
  stage(0, 0);
  asm volatile("" ::: "memory");
  loadB(0, B0);
  asm volatile("" ::: "memory");
  stage(1, 1);

  auto body = [&](int c, bf16x8 (&Bu)[2][2], bf16x8 (&Bn)[2][2]) {
    if (c == 15) asm volatile("s_waitcnt vmcnt(4)" ::: "memory");
    else         asm volatile("s_waitcnt vmcnt(6)" ::: "memory");
    __syncthreads();
    if (c < 15) loadB(c + 1, Bn);          // B before next stage (in-order vmcnt FIFO)
    asm volatile("" ::: "memory");
    if (c < 14) stage(c + 2, (c + 2) % 3);
    const char* Ab = smem + (c % 3) * CHB;
#pragma unroll
    for (int kl = 0; kl < 2; ++kl) {
      bf16x8 af[4];
#pragma unroll
      for (int fm = 0; fm < 4; ++fm)
        af[fm] = *(const bf16x8*)(Ab + (fm * 16 + l15) * 128 +
                                  ((kl * 64 + l4 * 16) ^ ((l15 & 7) << 4)));
#pragma unroll
      for (int fm = 0; fm < 4; ++fm) {
        acc[fm][0] = __builtin_amdgcn_mfma_f32_16x16x32_bf16(af[fm], Bu[0][kl], acc[fm][0], 0, 0, 0);
        acc[fm][1] = __builtin_amdgcn_mfma_f32_16x16x32_bf16(af[fm], Bu[1][kl], acc[fm][1], 0, 0, 0);
      }
    }
  };

  body(0, B0, B1);  body(1, B1, B0);  body(2, B0, B1);  body(3, B1, B0);
  body(4, B0, B1);  body(5, B1, B0);  body(6, B0, B1);  body(7, B1, B0);
  body(8, B0, B1);  body(9, B1, B0);  body(10, B0, B1); body(11, B1, B0);
  body(12, B0, B1); body(13, B1, B0); body(14, B0, B1); body(15, B1, B0);

  // atomic epilogue: out += acc + bias (out holds x2); no loads, no waits
#pragma unroll
  for (int fm = 0; fm < 4; ++fm)
#pragma unroll
    for (int r = 0; r < 4; ++r) {
      const long row = strip0 + fm * 16 + l4 * 4 + r;
      const long i0 = row * 256 + cg * 128 + w * 32 + l15;
      atomicAdd(&C[i0], acc[fm][0][r] + bias0);
      atomicAdd(&C[i0 + 16], acc[fm][1][r] + bias1);
    }
}

// ---------------- local window attention (head 0), one block per (window, batch) ----------------
__launch_bounds__(256)
__global__ void lattn_kernel(const bf16* __restrict__ qkv, bf16* __restrict__ attn) {
  const int j = blockIdx.x, b = blockIdx.y;
  const int tid = threadIdx.x, w = tid >> 6, lane = tid & 63;
  __shared__ bf16 Qs[64 * 40];
  __shared__ bf16 Ks[192 * 40];
  __shared__ bf16 Kt[32 * 200];
  __shared__ bf16 Ps[4][16 * 200];
  const float scale = 0.17677669529663687f;
  const long base = (long)b * 8192 + (long)j * 64;
  for (int i = tid; i < 64 * 32; i += 256) {
    const int r = i >> 5, d = i & 31;
    Qs[r * 40 + d] = (bf16)((float)qkv[(base + r) * 512 + d] * scale);
  }
  for (int i = tid; i < 192 * 32; i += 256) {
    const int c = i >> 5, d = i & 31;
    const long tc = (long)j * 64 - 64 + c;
    float kv = 0.f;
    if (tc >= 0 && tc < 8192) kv = (float)qkv[((long)b * 8192 + tc) * 512 + 256 + d];
    const bf16 kb = (bf16)kv;
    Ks[c * 40 + d] = kb;
    Kt[d * 200 + c] = kb;
  }
  __syncthreads();
  const int l15 = lane & 15, l4 = lane >> 4;
  const bf16x8 aq = *(const bf16x8*)(Qs + (w * 16 + l15) * 40 + l4 * 8);
  const f32x4 zz = {0.f, 0.f, 0.f, 0.f};
  f32x4 S[12];
#pragma unroll
  for (int fn = 0; fn < 12; ++fn) {
    const bf16x8 bk = *(const bf16x8*)(Ks + (fn * 16 + l15) * 40 + l4 * 8);
    S[fn] = __builtin_amdgcn_mfma_f32_16x16x32_bf16(aq, bk, zz, 0, 0, 0);
  }
#pragma unroll
  for (int fn = 0; fn < 12; ++fn) {
    const long tc = (long)j * 64 - 64 + fn * 16 + l15;
    if (tc < 0 || tc >= 8192) { S[fn][0] = -1e9f; S[fn][1] = -1e9f; S[fn][2] = -1e9f; S[fn][3] = -1e9f; }
  }
  float sinv[4];
#pragma unroll
  for (int r = 0; r < 4; ++r) {
    float m = -1e30f;
#pragma unroll
    for (int fn = 0; fn < 12; ++fn) m = fmaxf(m, S[fn][r]);
#pragma unroll
    for (int o = 1; o < 16; o <<= 1) m = fmaxf(m, __shfl_xor(m, o));
    float s = 0.f;
#pragma unroll
    for (int fn = 0; fn < 12; ++fn) { const float e = __expf(S[fn][r] - m); S[fn][r] = e; s += e; }
#pragma unroll
    for (int o = 1; o < 16; o <<= 1) s += __shfl_xor(s, o);
    sinv[r] = 1.f / s;
  }
#pragma unroll
  for (int fn = 0; fn < 12; ++fn)
#pragma unroll
    for (int r = 0; r < 4; ++r)
      Ps[w][(l4 * 4 + r) * 200 + fn * 16 + l15] = (bf16)(S[fn][r] * sinv[r]);
  __syncthreads();
  f32x4 O[2] = {};
#pragma unroll
  for (int ks = 0; ks < 6; ++ks) {
    const bf16x8 ap = *(const bf16x8*)(Ps[w] + l15 * 200 + ks * 32 + l4 * 8);
#pragma unroll
    for (int fe = 0; fe < 2; ++fe) {
      const bf16x8 bv = *(const bf16x8*)(Kt + (fe * 16 + l15) * 200 + ks * 32 + l4 * 8);
      O[fe] = __builtin_amdgcn_mfma_f32_16x16x32_bf16(ap, bv, O[fe], 0, 0, 0);
    }
  }
#pragma unroll
  for (int fe = 0; fe < 2; ++fe)
#pragma unroll
    for (int r = 0; r < 4; ++r)
      attn[(base + w * 16 + l4 * 4 + r) * 256 + fe * 16 + l15] = (bf16)O[fe][r];
}

// ---------------- linear attn ctx via MFMA (S via ones-row) ----------------
__launch_bounds__(256)
__global__ void ctx_kernel(const bf16* __restrict__ qkv, float* __restrict__ ctx,
                           float* __restrict__ S) {
  const int bh = blockIdx.x;
  const int b = bh / 7, h = bh % 7 + 1;
  const int tid = threadIdx.x;
  const int w = tid >> 6, lane = tid & 63;
  const int l15 = lane & 15, l4 = lane >> 4;
  __shared__ bf16 evT[32 * 264];
  __shared__ bf16 kT[48 * 264];
  __shared__ float red[4][32 * 48];
  const long n0 = (long)blockIdx.y * 256;
  const bf16* kp = qkv + ((long)b * 8192 + n0 + tid) * 512 + 256 + h * 32;
  bf16x8 kv[4];
#pragma unroll
  for (int c = 0; c < 4; ++c) kv[c] = *(const bf16x8*)(kp + c * 8);
#pragma unroll
  for (int i = 0; i < 16; ++i)
    kT[(32 + i) * 264 + tid] = (i == 0) ? (bf16)1.0f : (bf16)0.0f;
#pragma unroll
  for (int c = 0; c < 4; ++c)
#pragma unroll
    for (int j = 0; j < 8; ++j) {
      const int d = c * 8 + j;
      evT[d * 264 + tid] = (bf16)__expf((float)kv[c][j]);
      kT[d * 264 + tid] = kv[c][j];
    }
  __syncthreads();
  f32x4 acc[2][3] = {};
#pragma unroll
  for (int ks = 0; ks < 2; ++ks) {
    const int ncol = w * 64 + ks * 32 + l4 * 8;
    bf16x8 af[2], bb[3];
#pragma unroll
    for (int fm = 0; fm < 2; ++fm) af[fm] = *(const bf16x8*)(evT + (fm * 16 + l15) * 264 + ncol);
#pragma unroll
    for (int fe = 0; fe < 3; ++fe) bb[fe] = *(const bf16x8*)(kT + (fe * 16 + l15) * 264 + ncol);
#pragma unroll
    for (int fm = 0; fm < 2; ++fm)
#pragma unroll
      for (int fe = 0; fe < 3; ++fe)
        acc[fm][fe] = __builtin_amdgcn_mfma_f32_16x16x32_bf16(af[fm], bb[fe], acc[fm][fe], 0, 0, 0);
  }
#pragma unroll
  for (int fm = 0; fm < 2; ++fm)
#pragma unroll
    for (int fe = 0; fe < 3; ++fe)
#pragma unroll
      for (int r = 0; r < 4; ++r)
        red[w][(fm * 16 + l4 * 4 + r) * 48 + fe * 16 + l15] = acc[fm][fe][r];
  __syncthreads();
  for (int i = tid; i < 32 * 48; i += 256) {
    const float v = red[0][i] + red[1][i] + red[2][i] + red[3][i];
    const int d = i / 48, e = i - d * 48;
    if (e < 32) atomicAdd(ctx + (long)bh * 1024 + d * 32 + e, v);
    else if (e == 32) atomicAdd(S + bh * 32 + d, v);
  }
}

// ---------------- linear attn out via register softmax + MFMA ----------------
__launch_bounds__(256)
__global__ void lout_kernel(const bf16* __restrict__ qkv, const float* __restrict__ S,
                            const float* __restrict__ ctx, bf16* __restrict__ attn) {
  const int bh = blockIdx.x;
  const int b = bh / 7, h = bh % 7 + 1;
  const int tid = threadIdx.x;
  const int w = tid >> 6, lane = tid & 63;
  const int l15 = lane & 15, l4 = lane >> 4;
  __shared__ bf16 qs[256 * 40];
  __shared__ bf16 C2t[32 * 40];
  const long n0 = (long)blockIdx.y * 256;
  for (int i = tid; i < 1024; i += 256) {
    const int e = i >> 5, d = i & 31;
    C2t[e * 40 + d] = (bf16)(ctx[(long)bh * 1024 + d * 32 + e] / S[bh * 32 + d]);
  }
  const bf16* qp = qkv + ((long)b * 8192 + n0 + tid) * 512 + h * 32;
  bf16x8 qv[4];
#pragma unroll
  for (int c = 0; c < 4; ++c) qv[c] = *(const bf16x8*)(qp + c * 8);
  float qf[32];
#pragma unroll
  for (int c = 0; c < 4; ++c)
#pragma unroll
    for (int j = 0; j < 8; ++j) qf[c * 8 + j] = (float)qv[c][j];
  float m = qf[0];
#pragma unroll
  for (int d = 1; d < 32; ++d) m = fmaxf(m, qf[d]);
  float s = 0.f;
#pragma unroll
  for (int d = 0; d < 32; ++d) { qf[d] = __expf(qf[d] - m); s += qf[d]; }
  const float f = 0.17677669529663687f / s;
#pragma unroll
  for (int c = 0; c < 4; ++c) {
    bf16x8 o;
#pragma unroll
    for (int j = 0; j < 8; ++j) o[j] = (bf16)(qf[c * 8 + j] * f);
    *(bf16x8*)(qs + tid * 40 + c * 8) = o;
  }
  __syncthreads();
  f32x4 acc[4][2] = {};
  bf16x8 bfr[2];
#pragma unroll
  for (int fe = 0; fe < 2; ++fe) bfr[fe] = *(const bf16x8*)(C2t + (fe * 16 + l15) * 40 + l4 * 8);
#pragma unroll
  for (int fm = 0; fm < 4; ++fm) {
    const bf16x8 af = *(const bf16x8*)(qs + (w * 64 + fm * 16 + l15) * 40 + l4 * 8);
#pragma unroll
    for (int fe = 0; fe < 2; ++fe)
      acc[fm][fe] = __builtin_amdgcn_mfma_f32_16x16x32_bf16(af, bfr[fe], acc[fm][fe], 0, 0, 0);
  }
#pragma unroll
  for (int fm = 0; fm < 4; ++fm)
#pragma unroll
    for (int fe = 0; fe < 2; ++fe)
#pragma unroll
      for (int r = 0; r < 4; ++r)
        attn[((long)b * 8192 + n0 + w * 64 + fm * 16 + l4 * 4 + r) * 256 + h * 32 + fe * 16 + l15]
            = (bf16)acc[fm][fe][r];
}

extern "C" void kernel_launch(void* const* d_in, const int* in_sizes, int n_in,
                              void* d_out, int out_size, void* d_ws, size_t ws_size,
                              hipStream_t stream) {
  const float* x     = (const float*)d_in[0];
  const float* n1g   = (const float*)d_in[1];
  const float* n1b   = (const float*)d_in[2];
  const float* Wq    = (const float*)d_in[3];
  const float* Wkv   = (const float*)d_in[4];
  const float* Wproj = (const float*)d_in[5];
  const float* bproj = (const float*)d_in[6];
  const float* n2g   = (const float*)d_in[7];
  const float* n2b   = (const float*)d_in[8];
  const float* W1    = (const float*)d_in[9];
  const float* b1    = (const float*)d_in[10];
  const float* W2    = (const float*)d_in[11];
  const float* b2    = (const float*)d_in[12];
  float* out = (float*)d_out;
  char* ws = (char*)d_ws;

  bf16* wqkv   = (bf16*)(ws + 0);
  bf16* wprojb = (bf16*)(ws + 262144);
  bf16* w1b    = (bf16*)(ws + 393216);
  bf16* w2b    = (bf16*)(ws + 917504);
  float* Sbuf  = (float*)(ws + 1441792);   // 56*32 f32, contiguous with ctx for one memset
  float* ctx   = (float*)(ws + 1448960);   // 56*1024 f32
  bf16* hbuf   = (bf16*)(ws + 1685504);    // 65536x256 bf16 (h1 -> attn -> h2)
  bf16* qkv    = (bf16*)(ws + 35239936);   // 65536x512 bf16
  bf16* hidden = qkv;                      // 65536x1024 bf16 reuses qkv region

  cvt_weights<<<2816, 256, 0, stream>>>(Wq, Wkv, Wproj, W1, W2, wqkv, wprojb, w1b, w2b);
  ln_kernel<<<16384, 256, 0, stream>>>(x, n1g, n1b, hbuf);
  // qkv: [65536x512] = h1 @ WqkvT, K=256. NCG=4, MSPLIT=128 -> 512 blocks
  gemm_pb<0, 4, 2, 512, 128><<<512, 512, 0, stream>>>(hbuf, wqkv, qkv, nullptr, nullptr, 512);
  hipMemsetAsync(Sbuf, 0, 7168 + 229376, stream);
  lattn_kernel<<<dim3(128, 8), 256, 0, stream>>>(qkv, hbuf);
  ctx_kernel<<<dim3(56, 32), 256, 0, stream>>>(qkv, ctx, Sbuf);
  lout_kernel<<<dim3(56, 32), 256, 0, stream>>>(qkv, Sbuf, ctx, hbuf);
  // proj + residual: out f32 = attn @ WprojT + bproj + x. NCG=2, MSPLIT=256 -> 512 blocks
  gemm_pb<1, 2, 2, 512, 256><<<512, 512, 0, stream>>>(hbuf, wprojb, out, bproj, x, 256);
  ln_kernel<<<16384, 256, 0, stream>>>(out, n2g, n2b, hbuf);
  // mlp1: hidden bf16 = gelu(h2 @ W1T + b1). NCG=8, MSPLIT=64 -> 512 blocks
  gemm_pb<2, 8, 2, 512, 64><<<512, 512, 0, stream>>>(hbuf, w1b, hidden, b1, nullptr, 1024);
  // mlp2 + residual (high-occupancy atomic): out += hidden @ W2T + b2. 2048 blocks x 256 thr
  gemm_mlp2<<<2048, 256, 0, stream>>>(hidden, w2b, out, b2);
}

// Round 11
// 334.113 us; speedup vs baseline: 1.7911x; 1.0947x over previous
//
#include <hip/hip_runtime.h>
#include <hip/hip_bf16.h>

typedef __bf16 bf16;
typedef __bf16 bf16x8 __attribute__((ext_vector_type(8)));
typedef float f32x4 __attribute__((ext_vector_type(4)));

__device__ __forceinline__ void gld16(const void* g, void* l) {
  __builtin_amdgcn_global_load_lds((const __attribute__((address_space(1))) void*)g,
                                   (__attribute__((address_space(3))) void*)l, 16, 0, 0);
}

// ---------------- weight fp32 -> bf16 convert ----------------
__global__ void cvt_weights(const float* __restrict__ wq, const float* __restrict__ wkv,
                            const float* __restrict__ wp, const float* __restrict__ w1,
                            const float* __restrict__ w2,
                            bf16* __restrict__ wqkv, bf16* __restrict__ wpb,
                            bf16* __restrict__ w1b, bf16* __restrict__ w2b) {
  int i = blockIdx.x * 256 + threadIdx.x;
  if (i < 65536) wqkv[i] = (bf16)wq[i];
  else if (i < 131072) wqkv[i] = (bf16)wkv[i - 65536];
  else if (i < 196608) wpb[i - 131072] = (bf16)wp[i - 131072];
  else if (i < 458752) w1b[i - 196608] = (bf16)w1[i - 196608];
  else if (i < 720896) w2b[i - 458752] = (bf16)w2[i - 458752];
}

// ---------------- LayerNorm (wave per row, rows of 256) ----------------
__launch_bounds__(256)
__global__ void ln_kernel(const float* __restrict__ x, const float* __restrict__ g,
                          const float* __restrict__ b, bf16* __restrict__ out) {
  const int row = blockIdx.x * 4 + (threadIdx.x >> 6);
  const int lane = threadIdx.x & 63;
  const float4 v = ((const float4*)(x + (long)row * 256))[lane];
  float s = v.x + v.y + v.z + v.w;
#pragma unroll
  for (int o = 1; o < 64; o <<= 1) s += __shfl_xor(s, o);
  const float mu = s * (1.f / 256.f);
  const float dx = v.x - mu, dy = v.y - mu, dz = v.z - mu, dw = v.w - mu;
  float q = dx * dx + dy * dy + dz * dz + dw * dw;
#pragma unroll
  for (int o = 1; o < 64; o <<= 1) q += __shfl_xor(q, o);
  const float rstd = rsqrtf(q * (1.f / 256.f) + 1e-5f);
  const float4 gg = ((const float4*)g)[lane];
  const float4 bb = ((const float4*)b)[lane];
  union { bf16 h[4]; uint2 u; } pk;
  pk.h[0] = (bf16)(dx * rstd * gg.x + bb.x);
  pk.h[1] = (bf16)(dy * rstd * gg.y + bb.y);
  pk.h[2] = (bf16)(dz * rstd * gg.z + bb.z);
  pk.h[3] = (bf16)(dw * rstd * gg.w + bb.w);
  *(uint2*)(out + (long)row * 256 + lane * 4) = pk.u;
}

// ---------------- persistent-B pipelined GEMM (K=256 cases; R5-proven) ----------------
template <int EPI, int NCG, int NCHUNK, int THREADS, int MSPLIT>
__launch_bounds__(THREADS, 4)
__global__ void gemm_pb(const bf16* __restrict__ A, const bf16* __restrict__ Bw,
                        void* C, const float* __restrict__ bias,
                        const float* res, int ldC) {
  constexpr int WAVES = THREADS / 64;
  constexpr int WR = 2;
  constexpr int WC = WAVES / WR;
  constexpr int FN = 2;
  constexpr int FM = 64 / WR / 16;
  constexpr int COLS = WC * FN * 16;
  constexpr int KK = NCHUNK * 128;
  constexpr int ITER = 64 * 128 * 2 / (THREADS * 16);
  constexpr int TILES = 65536 / MSPLIT / 64;
  constexpr int CHB = 64 * 128 * 2;
  constexpr int BSZ = (EPI == 1) ? 64 * COLS * 4 : 64 * COLS * 2;
  constexpr int NST = (EPI == 1) ? 12 : 2;
  constexpr int NBLK = NCG * MSPLIT;
  __shared__ char smem[3 * CHB + BSZ];
  const int tid = threadIdx.x;
  const int w = tid >> 6, lane = tid & 63;
  const int l15 = lane & 15, l4 = lane >> 4;
  const int wrow = w & (WR - 1), wcol = w / WR;
  const int bid = blockIdx.x;
  const int slot = (bid & 7) * (NBLK / 8) + (bid >> 3);
  const int cg = slot % NCG;
  const long strip0 = (long)(slot / NCG) * (65536 / MSPLIT);

  const bf16* Bl = Bw + (long)(cg * COLS + wcol * FN * 16 + l15) * KK + l4 * 8;
  bf16x8 Breg[NCHUNK][4][FN];
#pragma unroll
  for (int c = 0; c < NCHUNK; ++c)
#pragma unroll
    for (int kl = 0; kl < 4; ++kl)
#pragma unroll
      for (int fn = 0; fn < FN; ++fn)
        Breg[c][kl][fn] = *(const bf16x8*)(Bl + (long)fn * 16 * KK + c * 128 + kl * 32);

  float bias_r[FN];
  if constexpr (EPI == 2) {
#pragma unroll
    for (int fn = 0; fn < FN; ++fn)
      bias_r[fn] = bias[cg * COLS + wcol * FN * 16 + fn * 16 + l15];
  }
  asm volatile("" ::: "memory");   // pin Breg/bias loads in the prologue

  auto stage = [&](int m, int c, int buf) {
#pragma unroll
    for (int it = 0; it < ITER; ++it) {
      const int p = it * (THREADS * 16) + tid * 16;
      const int row = p >> 8;
      const int colb = (p & 255) ^ ((row & 7) << 4);
      gld16((const char*)A + ((strip0 + m * 64 + row) * KK + c * 128) * 2 + colb,
            smem + buf * CHB + it * (THREADS * 16) + w * 1024);
    }
  };

  f32x4 acc[FM][FN] = {};
  stage(0, 0, 0);
  stage(0, 1, 1);

  for (int m = 0; m < TILES; ++m) {
#pragma unroll
    for (int c = 0; c < NCHUNK; ++c) {
      const int s = m * NCHUNK + c;
      if (m == 0 || c >= 2) {
        asm volatile("s_waitcnt vmcnt(%0)" ::"i"(ITER) : "memory");
      } else {
        asm volatile("s_waitcnt vmcnt(%0)" ::"i"(ITER + NST) : "memory");
      }
      __syncthreads();
      {
        int c2 = c + 2, m2 = m;
        if (c2 >= NCHUNK) { c2 -= NCHUNK; ++m2; }
        if (m2 < TILES) stage(m2, c2, (s + 2) % 3);
      }
      const char* Ab = smem + (s % 3) * CHB;
#pragma unroll
      for (int kl = 0; kl < 4; ++kl) {
        bf16x8 af[FM];
#pragma unroll
        for (int fm = 0; fm < FM; ++fm) {
          const int arow = wrow * (64 / WR) + fm * 16 + l15;
          af[fm] = *(const bf16x8*)(Ab + arow * 256 + ((kl * 64 + l4 * 16) ^ ((l15 & 7) << 4)));
        }
#pragma unroll
        for (int fm = 0; fm < FM; ++fm)
#pragma unroll
          for (int fn = 0; fn < FN; ++fn)
            acc[fm][fn] = __builtin_amdgcn_mfma_f32_16x16x32_bf16(af[fm], Breg[c][kl][fn],
                                                                  acc[fm][fn], 0, 0, 0);
      }
      if (c == NCHUNK - 1) {
        if constexpr (EPI == 1) {
          float* fb = (float*)(smem + 3 * CHB);
#pragma unroll
          for (int fm = 0; fm < FM; ++fm)
#pragma unroll
            for (int fn = 0; fn < FN; ++fn)
#pragma unroll
              for (int r = 0; r < 4; ++r)
                fb[(wrow * (64 / WR) + fm * 16 + l4 * 4 + r) * COLS +
                   wcol * FN * 16 + fn * 16 + l15] = acc[fm][fn][r];
          __syncthreads();
#pragma unroll
          for (int it = 0; it < 64 * COLS * 4 / (THREADS * 16); ++it) {
            const int off = it * (THREADS * 16) + tid * 16;
            const int row = off / (COLS * 4);
            const int colb = off % (COLS * 4);
            const long gb = ((strip0 + m * 64 + row) * ldC + cg * COLS) * 4 + colb;
            float4 v = *(const float4*)(smem + 3 * CHB + off);
            const float4 rr = *(const float4*)((const char*)res + gb);
            const float4 bv = *(const float4*)((const char*)bias + cg * COLS * 4 + colb);
            v.x += rr.x + bv.x; v.y += rr.y + bv.y;
            v.z += rr.z + bv.z; v.w += rr.w + bv.w;
            *(float4*)((char*)C + gb) = v;
          }
        } else {
          bf16* bb = (bf16*)(smem + 3 * CHB);
#pragma unroll
          for (int fm = 0; fm < FM; ++fm)
#pragma unroll
            for (int fn = 0; fn < FN; ++fn)
#pragma unroll
              for (int r = 0; r < 4; ++r) {
                float v = acc[fm][fn][r];
                if constexpr (EPI == 2) {
                  v += bias_r[fn];
                  v = 0.5f * v * (1.f + erff(v * 0.70710678118654752f));
                }
                bb[(wrow * (64 / WR) + fm * 16 + l4 * 4 + r) * COLS +
                   wcol * FN * 16 + fn * 16 + l15] = (bf16)v;
              }
          __syncthreads();
#pragma unroll
          for (int it = 0; it < 64 * COLS * 2 / (THREADS * 16); ++it) {
            const int off = it * (THREADS * 16) + tid * 16;
            const int row = off / (COLS * 2);
            const int colb = off % (COLS * 2);
            *(uint4*)((char*)C + ((strip0 + m * 64 + row) * ldC + cg * COLS) * 2 + colb) =
                *(const uint4*)(smem + 3 * CHB + off);
          }
        }
#pragma unroll
        for (int fm = 0; fm < FM; ++fm)
#pragma unroll
          for (int fn = 0; fn < FN; ++fn)
            acc[fm][fn] = f32x4{0.f, 0.f, 0.f, 0.f};
      }
    }
  }
}

// ---------------- mlp2 v4: full-width blocks, fat bodies, plain RMW epilogue ----------------
// out[65536x256] += hidden @ W2^T + b2 (out holds x2 residual). 1024 blocks x 256 thr.
// Each block owns 64 rows x ALL 256 cols (no atomics; exclusive rows). Wave w -> cols w*64..+63.
// Chunk = 64 rows x 64 K (8KB); 3 buffers = 24KB. FM=4, FN=4 -> 32 MFMA / 8 ds_read per
// wave-body (1:4). B double-buffered in two named 32-VGPR sets (residency law: <=64 ok).
// FIFO: wait vmcnt(10) [B(c)8 + stage(c+1)2] -> barrier -> loadB(c+1) -> stage(c+2) -> MFMA.
__launch_bounds__(256, 3)
__global__ void gemm_mlp2(const bf16* __restrict__ A, const bf16* __restrict__ Bw,
                          float* __restrict__ C, const float* __restrict__ bias) {
  constexpr int CHB = 64 * 64 * 2;   // 8KB chunk
  __shared__ char smem[3 * CHB];
  const int tid = threadIdx.x;
  const int w = tid >> 6, lane = tid & 63;
  const int l15 = lane & 15, l4 = lane >> 4;
  const int bid = blockIdx.x;                      // 1024 blocks
  const int slot = (bid & 7) * 128 + (bid >> 3);   // bijective XCD swizzle
  const long strip0 = (long)slot * 64;
  const int c0 = w * 64;                           // wave's column base
  const bf16* Bl = Bw + ((long)c0 + l15) * 1024 + l4 * 8;
  float biasr[4];
#pragma unroll
  for (int fn = 0; fn < 4; ++fn) biasr[fn] = bias[c0 + fn * 16 + l15];
  asm volatile("" ::: "memory");

  auto stage = [&](int c, int buf) {
#pragma unroll
    for (int it = 0; it < 2; ++it) {
      const int p = it * 4096 + tid * 16;
      const int row = p >> 7;                          // 128B rows (64 K bf16)
      const int colb = (p & 127) ^ ((row & 7) << 4);   // inverse swizzle at source
      gld16((const char*)A + ((strip0 + row) * 1024 + c * 64) * 2 + colb,
            smem + buf * CHB + it * 4096 + w * 1024);
    }
  };
  auto loadB = [&](int c, bf16x8 (&Bn)[4][2]) {
#pragma unroll
    for (int fn = 0; fn < 4; ++fn)
#pragma unroll
      for (int kl = 0; kl < 2; ++kl)
        Bn[fn][kl] = *(const bf16x8*)(Bl + (long)fn * 16 * 1024 + c * 64 + kl * 32);
  };

  bf16x8 B0[4][2], B1[4][2];
  f32x4 acc[4][4] = {};
  // prologue FIFO order: stage0, B0, stage1 (B0's compiler-wait must not force stage1)
  stage(0, 0);
  asm volatile("" ::: "memory");
  loadB(0, B0);
  asm volatile("" ::: "memory");
  stage(1, 1);

  auto body = [&](int c, bf16x8 (&Bu)[4][2], bf16x8 (&Bn)[4][2]) {
    if (c == 15) asm volatile("s_waitcnt vmcnt(8)" ::: "memory");
    else         asm volatile("s_waitcnt vmcnt(10)" ::: "memory");
    __syncthreads();
    if (c < 15) loadB(c + 1, Bn);          // B before next stage (in-order vmcnt FIFO)
    asm volatile("" ::: "memory");
    if (c < 14) stage(c + 2, (c + 2) % 3);
    const char* Ab = smem + (c % 3) * CHB;
#pragma unroll
    for (int kl = 0; kl < 2; ++kl) {
      bf16x8 af[4];
#pragma unroll
      for (int fm = 0; fm < 4; ++fm)
        af[fm] = *(const bf16x8*)(Ab + (fm * 16 + l15) * 128 +
                                  ((kl * 64 + l4 * 16) ^ ((l15 & 7) << 4)));
#pragma unroll
      for (int fm = 0; fm < 4; ++fm)
#pragma unroll
        for (int fn = 0; fn < 4; ++fn)
          acc[fm][fn] = __builtin_amdgcn_mfma_f32_16x16x32_bf16(af[fm], Bu[fn][kl],
                                                                acc[fm][fn], 0, 0, 0);
    }
  };

  body(0, B0, B1);  body(1, B1, B0);  body(2, B0, B1);  body(3, B1, B0);
  body(4, B0, B1);  body(5, B1, B0);  body(6, B0, B1);  body(7, B1, B0);
  body(8, B0, B1);  body(9, B1, B0);  body(10, B0, B1); body(11, B1, B0);
  body(12, B0, B1); body(13, B1, B0); body(14, B0, B1); body(15, B1, B0);

  // plain RMW epilogue (rows exclusive to this block): out += acc + bias
#pragma unroll
  for (int fm = 0; fm < 4; ++fm)
#pragma unroll
    for (int fn = 0; fn < 4; ++fn)
#pragma unroll
      for (int r = 0; r < 4; ++r) {
        const long row = strip0 + fm * 16 + l4 * 4 + r;
        const long idx = row * 256 + c0 + fn * 16 + l15;
        C[idx] = C[idx] + acc[fm][fn][r] + biasr[fn];
      }
}

// ---------------- local window attention (head 0), one block per (window, batch) ----------------
__launch_bounds__(256)
__global__ void lattn_kernel(const bf16* __restrict__ qkv, bf16* __restrict__ attn) {
  const int j = blockIdx.x, b = blockIdx.y;
  const int tid = threadIdx.x, w = tid >> 6, lane = tid & 63;
  __shared__ bf16 Qs[64 * 40];
  __shared__ bf16 Ks[192 * 40];
  __shared__ bf16 Kt[32 * 200];
  __shared__ bf16 Ps[4][16 * 200];
  const float scale = 0.17677669529663687f;
  const long base = (long)b * 8192 + (long)j * 64;
  for (int i = tid; i < 64 * 32; i += 256) {
    const int r = i >> 5, d = i & 31;
    Qs[r * 40 + d] = (bf16)((float)qkv[(base + r) * 512 + d] * scale);
  }
  for (int i = tid; i < 192 * 32; i += 256) {
    const int c = i >> 5, d = i & 31;
    const long tc = (long)j * 64 - 64 + c;
    float kv = 0.f;
    if (tc >= 0 && tc < 8192) kv = (float)qkv[((long)b * 8192 + tc) * 512 + 256 + d];
    const bf16 kb = (bf16)kv;
    Ks[c * 40 + d] = kb;
    Kt[d * 200 + c] = kb;
  }
  __syncthreads();
  const int l15 = lane & 15, l4 = lane >> 4;
  const bf16x8 aq = *(const bf16x8*)(Qs + (w * 16 + l15) * 40 + l4 * 8);
  const f32x4 zz = {0.f, 0.f, 0.f, 0.f};
  f32x4 S[12];
#pragma unroll
  for (int fn = 0; fn < 12; ++fn) {
    const bf16x8 bk = *(const bf16x8*)(Ks + (fn * 16 + l15) * 40 + l4 * 8);
    S[fn] = __builtin_amdgcn_mfma_f32_16x16x32_bf16(aq, bk, zz, 0, 0, 0);
  }
#pragma unroll
  for (int fn = 0; fn < 12; ++fn) {
    const long tc = (long)j * 64 - 64 + fn * 16 + l15;
    if (tc < 0 || tc >= 8192) { S[fn][0] = -1e9f; S[fn][1] = -1e9f; S[fn][2] = -1e9f; S[fn][3] = -1e9f; }
  }
  float sinv[4];
#pragma unroll
  for (int r = 0; r < 4; ++r) {
    float m = -1e30f;
#pragma unroll
    for (int fn = 0; fn < 12; ++fn) m = fmaxf(m, S[fn][r]);
#pragma unroll
    for (int o = 1; o < 16; o <<= 1) m = fmaxf(m, __shfl_xor(m, o));
    float s = 0.f;
#pragma unroll
    for (int fn = 0; fn < 12; ++fn) { const float e = __expf(S[fn][r] - m); S[fn][r] = e; s += e; }
#pragma unroll
    for (int o = 1; o < 16; o <<= 1) s += __shfl_xor(s, o);
    sinv[r] = 1.f / s;
  }
#pragma unroll
  for (int fn = 0; fn < 12; ++fn)
#pragma unroll
    for (int r = 0; r < 4; ++r)
      Ps[w][(l4 * 4 + r) * 200 + fn * 16 + l15] = (bf16)(S[fn][r] * sinv[r]);
  __syncthreads();
  f32x4 O[2] = {};
#pragma unroll
  for (int ks = 0; ks < 6; ++ks) {
    const bf16x8 ap = *(const bf16x8*)(Ps[w] + l15 * 200 + ks * 32 + l4 * 8);
#pragma unroll
    for (int fe = 0; fe < 2; ++fe) {
      const bf16x8 bv = *(const bf16x8*)(Kt + (fe * 16 + l15) * 200 + ks * 32 + l4 * 8);
      O[fe] = __builtin_amdgcn_mfma_f32_16x16x32_bf16(ap, bv, O[fe], 0, 0, 0);
    }
  }
#pragma unroll
  for (int fe = 0; fe < 2; ++fe)
#pragma unroll
    for (int r = 0; r < 4; ++r)
      attn[(base + w * 16 + l4 * 4 + r) * 256 + fe * 16 + l15] = (bf16)O[fe][r];
}

// ---------------- linear attn ctx via MFMA (S via ones-row) ----------------
__launch_bounds__(256)
__global__ void ctx_kernel(const bf16* __restrict__ qkv, float* __restrict__ ctx,
                           float* __restrict__ S) {
  const int bh = blockIdx.x;
  const int b = bh / 7, h = bh % 7 + 1;
  const int tid = threadIdx.x;
  const int w = tid >> 6, lane = tid & 63;
  const int l15 = lane & 15, l4 = lane >> 4;
  __shared__ bf16 evT[32 * 264];
  __shared__ bf16 kT[48 * 264];
  __shared__ float red[4][32 * 48];
  const long n0 = (long)blockIdx.y * 256;
  const bf16* kp = qkv + ((long)b * 8192 + n0 + tid) * 512 + 256 + h * 32;
  bf16x8 kv[4];
#pragma unroll
  for (int c = 0; c < 4; ++c) kv[c] = *(const bf16x8*)(kp + c * 8);
#pragma unroll
  for (int i = 0; i < 16; ++i)
    kT[(32 + i) * 264 + tid] = (i == 0) ? (bf16)1.0f : (bf16)0.0f;
#pragma unroll
  for (int c = 0; c < 4; ++c)
#pragma unroll
    for (int j = 0; j < 8; ++j) {
      const int d = c * 8 + j;
      evT[d * 264 + tid] = (bf16)__expf((float)kv[c][j]);
      kT[d * 264 + tid] = kv[c][j];
    }
  __syncthreads();
  f32x4 acc[2][3] = {};
#pragma unroll
  for (int ks = 0; ks < 2; ++ks) {
    const int ncol = w * 64 + ks * 32 + l4 * 8;
    bf16x8 af[2], bb[3];
#pragma unroll
    for (int fm = 0; fm < 2; ++fm) af[fm] = *(const bf16x8*)(evT + (fm * 16 + l15) * 264 + ncol);
#pragma unroll
    for (int fe = 0; fe < 3; ++fe) bb[fe] = *(const bf16x8*)(kT + (fe * 16 + l15) * 264 + ncol);
#pragma unroll
    for (int fm = 0; fm < 2; ++fm)
#pragma unroll
      for (int fe = 0; fe < 3; ++fe)
        acc[fm][fe] = __builtin_amdgcn_mfma_f32_16x16x32_bf16(af[fm], bb[fe], acc[fm][fe], 0, 0, 0);
  }
#pragma unroll
  for (int fm = 0; fm < 2; ++fm)
#pragma unroll
    for (int fe = 0; fe < 3; ++fe)
#pragma unroll
      for (int r = 0; r < 4; ++r)
        red[w][(fm * 16 + l4 * 4 + r) * 48 + fe * 16 + l15] = acc[fm][fe][r];
  __syncthreads();
  for (int i = tid; i < 32 * 48; i += 256) {
    const float v = red[0][i] + red[1][i] + red[2][i] + red[3][i];
    const int d = i / 48, e = i - d * 48;
    if (e < 32) atomicAdd(ctx + (long)bh * 1024 + d * 32 + e, v);
    else if (e == 32) atomicAdd(S + bh * 32 + d, v);
  }
}

// ---------------- linear attn out via register softmax + MFMA ----------------
__launch_bounds__(256)
__global__ void lout_kernel(const bf16* __restrict__ qkv, const float* __restrict__ S,
                            const float* __restrict__ ctx, bf16* __restrict__ attn) {
  const int bh = blockIdx.x;
  const int b = bh / 7, h = bh % 7 + 1;
  const int tid = threadIdx.x;
  const int w = tid >> 6, lane = tid & 63;
  const int l15 = lane & 15, l4 = lane >> 4;
  __shared__ bf16 qs[256 * 40];
  __shared__ bf16 C2t[32 * 40];
  const long n0 = (long)blockIdx.y * 256;
  for (int i = tid; i < 1024; i += 256) {
    const int e = i >> 5, d = i & 31;
    C2t[e * 40 + d] = (bf16)(ctx[(long)bh * 1024 + d * 32 + e] / S[bh * 32 + d]);
  }
  const bf16* qp = qkv + ((long)b * 8192 + n0 + tid) * 512 + h * 32;
  bf16x8 qv[4];
#pragma unroll
  for (int c = 0; c < 4; ++c) qv[c] = *(const bf16x8*)(qp + c * 8);
  float qf[32];
#pragma unroll
  for (int c = 0; c < 4; ++c)
#pragma unroll
    for (int j = 0; j < 8; ++j) qf[c * 8 + j] = (float)qv[c][j];
  float m = qf[0];
#pragma unroll
  for (int d = 1; d < 32; ++d) m = fmaxf(m, qf[d]);
  float s = 0.f;
#pragma unroll
  for (int d = 0; d < 32; ++d) { qf[d] = __expf(qf[d] - m); s += qf[d]; }
  const float f = 0.17677669529663687f / s;
#pragma unroll
  for (int c = 0; c < 4; ++c) {
    bf16x8 o;
#pragma unroll
    for (int j = 0; j < 8; ++j) o[j] = (bf16)(qf[c * 8 + j] * f);
    *(bf16x8*)(qs + tid * 40 + c * 8) = o;
  }
  __syncthreads();
  f32x4 acc[4][2] = {};
  bf16x8 bfr[2];
#pragma unroll
  for (int fe = 0; fe < 2; ++fe) bfr[fe] = *(const bf16x8*)(C2t + (fe * 16 + l15) * 40 + l4 * 8);
#pragma unroll
  for (int fm = 0; fm < 4; ++fm) {
    const bf16x8 af = *(const bf16x8*)(qs + (w * 64 + fm * 16 + l15) * 40 + l4 * 8);
#pragma unroll
    for (int fe = 0; fe < 2; ++fe)
      acc[fm][fe] = __builtin_amdgcn_mfma_f32_16x16x32_bf16(af, bfr[fe], acc[fm][fe], 0, 0, 0);
  }
#pragma unroll
  for (int fm = 0; fm < 4; ++fm)
#pragma unroll
    for (int fe = 0; fe < 2; ++fe)
#pragma unroll
      for (int r = 0; r < 4; ++r)
        attn[((long)b * 8192 + n0 + w * 64 + fm * 16 + l4 * 4 + r) * 256 + h * 32 + fe * 16 + l15]
            = (bf16)acc[fm][fe][r];
}

extern "C" void kernel_launch(void* const* d_in, const int* in_sizes, int n_in,
                              void* d_out, int out_size, void* d_ws, size_t ws_size,
                              hipStream_t stream) {
  const float* x     = (const float*)d_in[0];
  const float* n1g   = (const float*)d_in[1];
  const float* n1b   = (const float*)d_in[2];
  const float* Wq    = (const float*)d_in[3];
  const float* Wkv   = (const float*)d_in[4];
  const float* Wproj = (const float*)d_in[5];
  const float* bproj = (const float*)d_in[6];
  const float* n2g   = (const float*)d_in[7];
  const float* n2b   = (const float*)d_in[8];
  const float* W1    = (const float*)d_in[9];
  const float* b1    = (const float*)d_in[10];
  const float* W2    = (const float*)d_in[11];
  const float* b2    = (const float*)d_in[12];
  float* out = (float*)d_out;
  char* ws = (char*)d_ws;

  bf16* wqkv   = (bf16*)(ws + 0);
  bf16* wprojb = (bf16*)(ws + 262144);
  bf16* w1b    = (bf16*)(ws + 393216);
  bf16* w2b    = (bf16*)(ws + 917504);
  float* Sbuf  = (float*)(ws + 1441792);   // 56*32 f32, contiguous with ctx for one memset
  float* ctx   = (float*)(ws + 1448960);   // 56*1024 f32
  bf16* hbuf   = (bf16*)(ws + 1685504);    // 65536x256 bf16 (h1 -> attn -> h2)
  bf16* qkv    = (bf16*)(ws + 35239936);   // 65536x512 bf16
  bf16* hidden = qkv;                      // 65536x1024 bf16 reuses qkv region

  cvt_weights<<<2816, 256, 0, stream>>>(Wq, Wkv, Wproj, W1, W2, wqkv, wprojb, w1b, w2b);
  ln_kernel<<<16384, 256, 0, stream>>>(x, n1g, n1b, hbuf);
  // qkv: [65536x512] = h1 @ WqkvT, K=256. NCG=4, MSPLIT=128 -> 512 blocks
  gemm_pb<0, 4, 2, 512, 128><<<512, 512, 0, stream>>>(hbuf, wqkv, qkv, nullptr, nullptr, 512);
  hipMemsetAsync(Sbuf, 0, 7168 + 229376, stream);
  lattn_kernel<<<dim3(128, 8), 256, 0, stream>>>(qkv, hbuf);
  ctx_kernel<<<dim3(56, 32), 256, 0, stream>>>(qkv, ctx, Sbuf);
  lout_kernel<<<dim3(56, 32), 256, 0, stream>>>(qkv, Sbuf, ctx, hbuf);
  // proj + residual: out f32 = attn @ WprojT + bproj + x. NCG=2, MSPLIT=256 -> 512 blocks
  gemm_pb<1, 2, 2, 512, 256><<<512, 512, 0, stream>>>(hbuf, wprojb, out, bproj, x, 256);
  ln_kernel<<<16384, 256, 0, stream>>>(out, n2g, n2b, hbuf);
  // mlp1: hidden bf16 = gelu(h2 @ W1T + b1). NCG=8, MSPLIT=64 -> 512 blocks
  gemm_pb<2, 8, 2, 512, 64><<<512, 512, 0, stream>>>(hbuf, w1b, hidden, b1, nullptr, 1024);
  // mlp2 + residual (full-width blocks, plain RMW): out += hidden @ W2T + b2. 1024 blocks
  gemm_mlp2<<<1024, 256, 0, stream>>>(hidden, w2b, out, b2);
}